// Round 3
// baseline (144.508 us; speedup 1.0000x reference)
//
#include <hip/hip_runtime.h>
#include <hip/hip_bf16.h>

#define BSZ   4
#define LSEQ  1024
#define NH    12
#define DDIM  768
#define NEN   42
#define NM    96
#define NPAIR (NEN*NEN)   /* 1764 */
#define OFF   1

typedef short bf16x8 __attribute__((ext_vector_type(8)));
typedef float f32x4  __attribute__((ext_vector_type(4)));

// ---------------- workspace layout ----------------
// floats: e_emb | e_att | invS      then bf16: ptil | seqT
#define EMB_CNT  (BSZ*NEN*DDIM)
#define EATT_CNT (BSZ*NEN*NH*LSEQ)
#define INVS_CNT (BSZ*NPAIR)
#define FLOAT_CNT (EMB_CNT + EATT_CNT + INVS_CNT)
#define PTIL_CNT ((size_t)BSZ*NPAIR*LSEQ)

// ---------------- kernel 1: entity embeddings (segment logsumexp) -------------
__global__ void ent_emb_kernel(const float* __restrict__ seq,
                               const int* __restrict__ mpos,
                               const int* __restrict__ ment,
                               float* __restrict__ e_emb) {
    int b = blockIdx.x / NEN, e = blockIdx.x % NEN;
    __shared__ int sp[NM];
    __shared__ int se[NM];
    int t = threadIdx.x;
    if (t < NM) { sp[t] = mpos[b*NM + t] + OFF; se[t] = ment[b*NM + t]; }
    __syncthreads();
    const float* sq = seq + (size_t)b * LSEQ * DDIM;
    for (int d = t; d < DDIM; d += blockDim.x) {
        float mx = -1e30f; int cnt = 0;
        for (int m = 0; m < NM; ++m)
            if (se[m] == e) { ++cnt; mx = fmaxf(mx, sq[(size_t)sp[m]*DDIM + d]); }
        float out = 0.f;
        if (cnt) {
            float s = 0.f;
            for (int m = 0; m < NM; ++m)
                if (se[m] == e) s += expf(sq[(size_t)sp[m]*DDIM + d] - mx);
            out = logf(fmaxf(s, 1e-30f)) + mx;
        }
        e_emb[((size_t)b*NEN + e)*DDIM + d] = out;
    }
}

// ---------------- kernel 2: entity attentions (segment mean) ------------------
__global__ void ent_att_kernel(const float* __restrict__ att,
                               const int* __restrict__ mpos,
                               const int* __restrict__ ment,
                               float* __restrict__ e_att) {
    int id = blockIdx.x;
    int h = id % NH;
    int e = (id / NH) % NEN;
    int b = id / (NH * NEN);
    __shared__ int sp[NM];
    __shared__ int se[NM];
    int t = threadIdx.x;
    if (t < NM) { sp[t] = mpos[b*NM + t] + OFF; se[t] = ment[b*NM + t]; }
    __syncthreads();
    const float* ab = att + ((size_t)(b*NH + h)) * LSEQ * LSEQ;
    float4 acc = {0.f, 0.f, 0.f, 0.f};
    int cnt = 0;
    for (int m = 0; m < NM; ++m) {
        if (se[m] == e) {
            ++cnt;
            float4 v = ((const float4*)(ab + (size_t)sp[m]*LSEQ))[t];
            acc.x += v.x; acc.y += v.y; acc.z += v.z; acc.w += v.w;
        }
    }
    float inv = cnt ? 1.f / (float)cnt : 0.f;
    acc.x *= inv; acc.y *= inv; acc.z *= inv; acc.w *= inv;
    ((float4*)(e_att + ((size_t)(b*NEN + e)*NH + h)*LSEQ))[t] = acc;
}

// ---------------- kernel 3: pair products p~ (bf16), LDS-staged --------------
// block: (l-chunk of 16, doc). Stage E[42][12][16] in LDS; thread (a, lq)
// caches its a-row in regs, loops over all b (LDS broadcast reads).
#define LCH 16
__global__ __launch_bounds__(192) void pair2_kernel(
        const float* __restrict__ e_att,
        __hip_bfloat16* __restrict__ ptil) {
    int lc = blockIdx.x, b = blockIdx.y;
    int l0 = lc * LCH;
    __shared__ float E[NEN][NH][LCH + 4];          // 42*12*20*4 = 40320 B
    const float* src = e_att + (size_t)b * NEN * NH * LSEQ;
    for (int f = threadIdx.x; f < NEN * NH * (LCH/4); f += 192) {
        int q  = f & 3;
        int eh = f >> 2;
        float4 v = *(const float4*)(src + (size_t)eh * LSEQ + l0 + q*4);
        *(float4*)&E[eh / NH][eh % NH][q*4] = v;
    }
    __syncthreads();
    if (threadIdx.x >= NEN * 4) return;            // 168 active
    int a  = threadIdx.x % NEN;
    int lq = threadIdx.x / NEN;                    // 0..3
    float4 xa[NH];
    #pragma unroll
    for (int h = 0; h < NH; ++h) xa[h] = *(float4*)&E[a][h][lq*4];
    __hip_bfloat16* dst = ptil + ((size_t)b * NPAIR + a * NEN) * LSEQ + l0 + lq*4;
    for (int bb = 0; bb < NEN; ++bb) {
        float4 s = {0.f, 0.f, 0.f, 0.f};
        #pragma unroll
        for (int h = 0; h < NH; ++h) {
            float4 y = *(float4*)&E[bb][h][lq*4];  // wave-uniform: broadcast
            s.x += xa[h].x * y.x; s.y += xa[h].y * y.y;
            s.z += xa[h].z * y.z; s.w += xa[h].w * y.w;
        }
        union { ushort4 u4; __hip_bfloat16 hh[4]; } pk;
        pk.hh[0] = __float2bfloat16(s.x);
        pk.hh[1] = __float2bfloat16(s.y);
        pk.hh[2] = __float2bfloat16(s.z);
        pk.hh[3] = __float2bfloat16(s.w);
        *(ushort4*)(dst + (size_t)bb * LSEQ) = pk.u4;
    }
}

// ---------------- kernel 3b: row sums of ptil -> invS ------------------------
__global__ __launch_bounds__(256) void rowsum_kernel(
        const __hip_bfloat16* __restrict__ ptil,
        float* __restrict__ invS) {
    int row  = blockIdx.x * 4 + (threadIdx.x >> 6);   // [0, BSZ*NPAIR)
    int lane = threadIdx.x & 63;
    const __hip_bfloat16* p = ptil + (size_t)row * LSEQ;
    float s = 0.f;
    #pragma unroll
    for (int i = 0; i < LSEQ / (64*8); ++i) {
        bf16x8 v = *(const bf16x8*)(p + (i*64 + lane) * 8);
        #pragma unroll
        for (int j = 0; j < 8; ++j) {
            union { unsigned u; float f; } c;
            c.u = ((unsigned)(unsigned short)v[j]) << 16;
            s += c.f;
        }
    }
    #pragma unroll
    for (int o = 32; o > 0; o >>= 1) s += __shfl_down(s, o, 64);
    if (lane == 0) invS[row] = 1.f / (s + (float)NH * 1e-5f);
}

// ---------------- kernel 4: gather hss / tss ---------------------------------
__global__ void gather_ht_kernel(const float* __restrict__ e_emb,
                                 const int* __restrict__ hts,
                                 float* __restrict__ out_h,
                                 float* __restrict__ out_t) {
    int id = blockIdx.x;                 // b*NPAIR + p
    int b  = id / NPAIR;
    int hi = hts[id*2 + 0];
    int ti = hts[id*2 + 1];
    const float4* eh = (const float4*)(e_emb + ((size_t)(b*NEN + hi))*DDIM);
    const float4* et = (const float4*)(e_emb + ((size_t)(b*NEN + ti))*DDIM);
    float4* oh = (float4*)(out_h + (size_t)id*DDIM);
    float4* ot = (float4*)(out_t + (size_t)id*DDIM);
    int t = threadIdx.x;
    if (t < DDIM/4) { oh[t] = eh[t]; ot[t] = et[t]; }
}

// ---------------- kernel 5: seq f32 [L][D] -> seqT bf16 [D][L] ---------------
__global__ void seq2bf16T_kernel(const float* __restrict__ seq,
                                 __hip_bfloat16* __restrict__ seqT) {
    int b  = blockIdx.z;
    int l0 = blockIdx.x * 32;
    int d0 = blockIdx.y * 32;
    __shared__ float tile[32][33];
    int t = threadIdx.x;
    int l = t >> 3, dq = (t & 7) * 4;
    float4 v = *(const float4*)(seq + ((size_t)b*LSEQ + l0 + l)*DDIM + d0 + dq);
    tile[l][dq+0] = v.x; tile[l][dq+1] = v.y; tile[l][dq+2] = v.z; tile[l][dq+3] = v.w;
    __syncthreads();
    int d = t >> 3, lq = (t & 7) * 4;
    union { ushort4 u4; __hip_bfloat16 h[4]; } pk;
    pk.h[0] = __float2bfloat16(tile[lq+0][d]);
    pk.h[1] = __float2bfloat16(tile[lq+1][d]);
    pk.h[2] = __float2bfloat16(tile[lq+2][d]);
    pk.h[3] = __float2bfloat16(tile[lq+3][d]);
    *(ushort4*)(seqT + ((size_t)b*DDIM + d0 + d)*LSEQ + l0 + lq) = pk.u4;
}

// ---------------- kernel 6: fmap GEMM (MFMA bf16)  C = (ptil @ seq) * invS ---
#define BM 128
#define BN 64
#define BK 64
#define MT 14           /* ceil(1764/128) */
#define NT (DDIM/BN)    /* 12 */

__global__ __launch_bounds__(256) void fmap_mfma_kernel(
        const __hip_bfloat16* __restrict__ ptil,
        const __hip_bfloat16* __restrict__ seqT,
        const float* __restrict__ invS,
        float* __restrict__ fmap) {
    __shared__ __hip_bfloat16 As[BM][BK + 8];   // 128 x 72  (padded: conflict-free)
    __shared__ __hip_bfloat16 Bs[BN][BK + 8];   // 64 x 72   (col-major tile: Bs[col][k])

    const int t    = threadIdx.x;
    const int lane = t & 63;
    const int wid  = t >> 6;
    const int wr   = wid >> 1;      // 0..1 : 64-row half
    const int wc   = wid & 1;       // 0..1 : 32-col half
    const int bx = blockIdx.x, by = blockIdx.y, b = blockIdx.z;
    const int r0 = bx * BM, c0 = by * BN;

    const __hip_bfloat16* A  = ptil + (size_t)b * NPAIR * LSEQ;
    const __hip_bfloat16* Bt = seqT + (size_t)b * DDIM * LSEQ;

    // staging indices
    const int ar = t >> 1;            // A row 0..127
    const int ae = (t & 1) * 32;      // A elem offset (covers 32 elems = 64B)
    const int bc = t >> 2;            // B col 0..63
    const int bq = (t & 3) * 16;      // B elem offset (covers 16 elems = 32B)

    const f32x4 zero = {0.f, 0.f, 0.f, 0.f};
    f32x4 acc[4][2];
    #pragma unroll
    for (int m = 0; m < 4; ++m)
        #pragma unroll
        for (int n = 0; n < 2; ++n) acc[m][n] = zero;

    const int fr = lane & 15, kg = lane >> 4;

    for (int k0 = 0; k0 < LSEQ; k0 += BK) {
        // ---- stage A (128 x 64 bf16) ----
        int gr = r0 + ar;
        if (gr < NPAIR) {
            const __hip_bfloat16* src = A + (size_t)gr * LSEQ + k0 + ae;
            uint4 r0v = *(const uint4*)(src +  0);
            uint4 r1v = *(const uint4*)(src +  8);
            uint4 r2v = *(const uint4*)(src + 16);
            uint4 r3v = *(const uint4*)(src + 24);
            *(uint4*)(&As[ar][ae +  0]) = r0v;
            *(uint4*)(&As[ar][ae +  8]) = r1v;
            *(uint4*)(&As[ar][ae + 16]) = r2v;
            *(uint4*)(&As[ar][ae + 24]) = r3v;
        } else {
            uint4 z = {0u, 0u, 0u, 0u};
            *(uint4*)(&As[ar][ae +  0]) = z;
            *(uint4*)(&As[ar][ae +  8]) = z;
            *(uint4*)(&As[ar][ae + 16]) = z;
            *(uint4*)(&As[ar][ae + 24]) = z;
        }
        // ---- stage B^T (64 cols x 64 k) ----
        {
            const __hip_bfloat16* src = Bt + (size_t)(c0 + bc) * LSEQ + k0 + bq;
            uint4 b0v = *(const uint4*)(src + 0);
            uint4 b1v = *(const uint4*)(src + 8);
            *(uint4*)(&Bs[bc][bq + 0]) = b0v;
            *(uint4*)(&Bs[bc][bq + 8]) = b1v;
        }
        __syncthreads();

        // ---- MFMA: 2 K-chunks of 32, 4x2 fragments ----
        #pragma unroll
        for (int ks = 0; ks < 2; ++ks) {
            bf16x8 af[4], bfv[2];
            #pragma unroll
            for (int m = 0; m < 4; ++m)
                af[m] = *(const bf16x8*)(&As[wr*64 + m*16 + fr][ks*32 + kg*8]);
            #pragma unroll
            for (int n = 0; n < 2; ++n)
                bfv[n] = *(const bf16x8*)(&Bs[wc*32 + n*16 + fr][ks*32 + kg*8]);
            #pragma unroll
            for (int m = 0; m < 4; ++m)
                #pragma unroll
                for (int n = 0; n < 2; ++n)
                    acc[m][n] = __builtin_amdgcn_mfma_f32_16x16x32_bf16(
                                    af[m], bfv[n], acc[m][n], 0, 0, 0);
        }
        __syncthreads();
    }

    // ---- epilogue: scale by invS[row], store ----
    #pragma unroll
    for (int m = 0; m < 4; ++m) {
        int rb = r0 + wr*64 + m*16 + kg*4;
        #pragma unroll
        for (int n = 0; n < 2; ++n) {
            int col = c0 + wc*32 + n*16 + fr;
            #pragma unroll
            for (int i = 0; i < 4; ++i) {
                int row = rb + i;
                if (row < NPAIR) {
                    float sc = invS[b*NPAIR + row];
                    fmap[((size_t)b*NPAIR + row)*DDIM + col] = acc[m][n][i] * sc;
                }
            }
        }
    }
}

// ---------------- launcher ---------------------------------------------------
extern "C" void kernel_launch(void* const* d_in, const int* in_sizes, int n_in,
                              void* d_out, int out_size, void* d_ws, size_t ws_size,
                              hipStream_t stream) {
    const float* seq  = (const float*)d_in[0];
    const float* att  = (const float*)d_in[1];
    const int*   mpos = (const int*)d_in[2];
    const int*   ment = (const int*)d_in[3];
    const int*   hts  = (const int*)d_in[4];

    float* ws_f  = (float*)d_ws;
    float* e_emb = ws_f;
    float* e_att = ws_f + EMB_CNT;
    float* invS  = ws_f + EMB_CNT + EATT_CNT;
    __hip_bfloat16* ptil = (__hip_bfloat16*)(ws_f + FLOAT_CNT);
    __hip_bfloat16* seqT = ptil + PTIL_CNT;

    float* out_h = (float*)d_out;
    float* out_t = out_h + (size_t)BSZ*NPAIR*DDIM;
    float* fmap  = out_t + (size_t)BSZ*NPAIR*DDIM;

    hipLaunchKernelGGL(ent_emb_kernel, dim3(BSZ*NEN), dim3(256), 0, stream,
                       seq, mpos, ment, e_emb);
    hipLaunchKernelGGL(ent_att_kernel, dim3(BSZ*NEN*NH), dim3(256), 0, stream,
                       att, mpos, ment, e_att);
    hipLaunchKernelGGL(pair2_kernel, dim3(LSEQ/LCH, BSZ), dim3(192), 0, stream,
                       e_att, ptil);
    hipLaunchKernelGGL(rowsum_kernel, dim3(BSZ*NPAIR/4), dim3(256), 0, stream,
                       ptil, invS);
    hipLaunchKernelGGL(gather_ht_kernel, dim3(BSZ*NPAIR), dim3(256), 0, stream,
                       e_emb, hts, out_h, out_t);
    hipLaunchKernelGGL(seq2bf16T_kernel, dim3(LSEQ/32, DDIM/32, BSZ),
                       dim3(256), 0, stream, seq, seqT);
    hipLaunchKernelGGL(fmap_mfma_kernel, dim3(MT, NT, BSZ),
                       dim3(256), 0, stream, ptil, seqT, invS, fmap);
}

// Round 4
// 121.241 us; speedup vs baseline: 1.1919x; 1.1919x over previous
//
#include <hip/hip_runtime.h>
#include <hip/hip_bf16.h>

#define BSZ   4
#define LSEQ  1024
#define NH    12
#define DDIM  768
#define NEN   42
#define NM    96
#define NPAIR (NEN*NEN)   /* 1764 */
#define NTRI  (NEN*(NEN+1)/2)  /* 903 */
#define OFF   1

typedef short bf16x8 __attribute__((ext_vector_type(8)));
typedef float f32x4  __attribute__((ext_vector_type(4)));

// ---------------- workspace layout ----------------
#define EMB_CNT  (BSZ*NEN*DDIM)
#define EATT_CNT (BSZ*NEN*NH*LSEQ)
#define INVS_CNT (BSZ*NPAIR)
#define FLOAT_CNT (EMB_CNT + EATT_CNT + INVS_CNT)
#define PTIL_CNT ((size_t)BSZ*NPAIR*LSEQ)

// ---------------- kernel 1: entity embeddings (segment logsumexp) -------------
__global__ void ent_emb_kernel(const float* __restrict__ seq,
                               const int* __restrict__ mpos,
                               const int* __restrict__ ment,
                               float* __restrict__ e_emb) {
    int b = blockIdx.x / NEN, e = blockIdx.x % NEN;
    __shared__ int sp[NM];
    __shared__ int se[NM];
    int t = threadIdx.x;
    if (t < NM) { sp[t] = mpos[b*NM + t] + OFF; se[t] = ment[b*NM + t]; }
    __syncthreads();
    const float* sq = seq + (size_t)b * LSEQ * DDIM;
    for (int d = t; d < DDIM; d += blockDim.x) {
        float mx = -1e30f; int cnt = 0;
        for (int m = 0; m < NM; ++m)
            if (se[m] == e) { ++cnt; mx = fmaxf(mx, sq[(size_t)sp[m]*DDIM + d]); }
        float out = 0.f;
        if (cnt) {
            float s = 0.f;
            for (int m = 0; m < NM; ++m)
                if (se[m] == e) s += expf(sq[(size_t)sp[m]*DDIM + d] - mx);
            out = logf(fmaxf(s, 1e-30f)) + mx;
        }
        e_emb[((size_t)b*NEN + e)*DDIM + d] = out;
    }
}

// ---------------- kernel 2: entity attentions (segment mean) ------------------
__global__ void ent_att_kernel(const float* __restrict__ att,
                               const int* __restrict__ mpos,
                               const int* __restrict__ ment,
                               float* __restrict__ e_att) {
    int id = blockIdx.x;
    int h = id % NH;
    int e = (id / NH) % NEN;
    int b = id / (NH * NEN);
    __shared__ int sp[NM];
    __shared__ int se[NM];
    int t = threadIdx.x;
    if (t < NM) { sp[t] = mpos[b*NM + t] + OFF; se[t] = ment[b*NM + t]; }
    __syncthreads();
    const float* ab = att + ((size_t)(b*NH + h)) * LSEQ * LSEQ;
    float4 acc = {0.f, 0.f, 0.f, 0.f};
    int cnt = 0;
    for (int m = 0; m < NM; ++m) {
        if (se[m] == e) {
            ++cnt;
            float4 v = ((const float4*)(ab + (size_t)sp[m]*LSEQ))[t];
            acc.x += v.x; acc.y += v.y; acc.z += v.z; acc.w += v.w;
        }
    }
    float inv = cnt ? 1.f / (float)cnt : 0.f;
    acc.x *= inv; acc.y *= inv; acc.z *= inv; acc.w *= inv;
    ((float4*)(e_att + ((size_t)(b*NEN + e)*NH + h)*LSEQ))[t] = acc;
}

// ---------------- kernel 3: symmetric pair products + invS -------------------
// one block per triangular pair (a<=bb); writes both rows of ptil and invS.
__global__ __launch_bounds__(256) void pair_sym_kernel(
        const float* __restrict__ e_att,
        __hip_bfloat16* __restrict__ ptil,
        float* __restrict__ invS) {
    int tri = blockIdx.x;          // 0..902
    int b   = blockIdx.y;
    int a = 0, rem = tri;
    while (rem >= NEN - a) { rem -= NEN - a; ++a; }   // uniform scalar loop
    int bb = a + rem;
    int t = threadIdx.x;           // 256 threads x float4 = 1024 l
    const float4* ra = (const float4*)(e_att + ((size_t)(b*NEN + a )*NH)*LSEQ);
    const float4* rb = (const float4*)(e_att + ((size_t)(b*NEN + bb)*NH)*LSEQ);
    float4 acc = {0.f, 0.f, 0.f, 0.f};
    #pragma unroll
    for (int h = 0; h < NH; ++h) {
        float4 x = ra[h*(LSEQ/4) + t];
        float4 y = rb[h*(LSEQ/4) + t];
        acc.x += x.x*y.x; acc.y += x.y*y.y; acc.z += x.z*y.z; acc.w += x.w*y.w;
    }
    union { ushort4 u4; __hip_bfloat16 hh[4]; } pk;
    pk.hh[0] = __float2bfloat16(acc.x);
    pk.hh[1] = __float2bfloat16(acc.y);
    pk.hh[2] = __float2bfloat16(acc.z);
    pk.hh[3] = __float2bfloat16(acc.w);
    __hip_bfloat16* base = ptil + (size_t)b * NPAIR * LSEQ;
    *(ushort4*)(base + (size_t)(a*NEN + bb)*LSEQ + t*4) = pk.u4;
    if (a != bb)
        *(ushort4*)(base + (size_t)(bb*NEN + a)*LSEQ + t*4) = pk.u4;

    // block reduction of sum_l p  ->  invS = 1/(sum + H*1e-5)
    float s = acc.x + acc.y + acc.z + acc.w;
    #pragma unroll
    for (int o = 32; o > 0; o >>= 1) s += __shfl_down(s, o, 64);
    __shared__ float red[4];
    if ((t & 63) == 0) red[t >> 6] = s;
    __syncthreads();
    if (t == 0) {
        float tot = red[0] + red[1] + red[2] + red[3];
        float v = 1.f / (tot + (float)NH * 1e-5f);
        invS[b*NPAIR + a*NEN + bb] = v;
        if (a != bb) invS[b*NPAIR + bb*NEN + a] = v;
    }
}

// ---------------- kernel 4: gather hss / tss ---------------------------------
__global__ void gather_ht_kernel(const float* __restrict__ e_emb,
                                 const int* __restrict__ hts,
                                 float* __restrict__ out_h,
                                 float* __restrict__ out_t) {
    int id = blockIdx.x;                 // b*NPAIR + p
    int b  = id / NPAIR;
    int hi = hts[id*2 + 0];
    int ti = hts[id*2 + 1];
    const float4* eh = (const float4*)(e_emb + ((size_t)(b*NEN + hi))*DDIM);
    const float4* et = (const float4*)(e_emb + ((size_t)(b*NEN + ti))*DDIM);
    float4* oh = (float4*)(out_h + (size_t)id*DDIM);
    float4* ot = (float4*)(out_t + (size_t)id*DDIM);
    int t = threadIdx.x;
    if (t < DDIM/4) { oh[t] = eh[t]; ot[t] = et[t]; }
}

// ---------------- kernel 5: seq f32 [L][D] -> seqT bf16 [D][L] ---------------
__global__ void seq2bf16T_kernel(const float* __restrict__ seq,
                                 __hip_bfloat16* __restrict__ seqT) {
    int b  = blockIdx.z;
    int l0 = blockIdx.x * 32;
    int d0 = blockIdx.y * 32;
    __shared__ float tile[32][33];
    int t = threadIdx.x;
    int l = t >> 3, dq = (t & 7) * 4;
    float4 v = *(const float4*)(seq + ((size_t)b*LSEQ + l0 + l)*DDIM + d0 + dq);
    tile[l][dq+0] = v.x; tile[l][dq+1] = v.y; tile[l][dq+2] = v.z; tile[l][dq+3] = v.w;
    __syncthreads();
    int d = t >> 3, lq = (t & 7) * 4;
    union { ushort4 u4; __hip_bfloat16 h[4]; } pk;
    pk.h[0] = __float2bfloat16(tile[lq+0][d]);
    pk.h[1] = __float2bfloat16(tile[lq+1][d]);
    pk.h[2] = __float2bfloat16(tile[lq+2][d]);
    pk.h[3] = __float2bfloat16(tile[lq+3][d]);
    *(ushort4*)(seqT + ((size_t)b*DDIM + d0 + d)*LSEQ + l0 + lq) = pk.u4;
}

// ---------------- kernel 6: fmap GEMM (MFMA bf16)  C = (ptil @ seq) * invS ---
#define BM 128
#define BN 128
#define BK 64
#define MT 14           /* ceil(1764/128) */
#define NT (DDIM/BN)    /* 6 */

__global__ __launch_bounds__(256) void fmap_mfma_kernel(
        const __hip_bfloat16* __restrict__ ptil,
        const __hip_bfloat16* __restrict__ seqT,
        const float* __restrict__ invS,
        float* __restrict__ fmap) {
    __shared__ __hip_bfloat16 As[BM][BK + 8];   // 128 x 72
    __shared__ __hip_bfloat16 Bs[BN][BK + 8];   // 128 x 72 (col-major: Bs[col][k])

    const int t    = threadIdx.x;
    const int lane = t & 63;
    const int wid  = t >> 6;
    const int wr   = wid >> 1;      // 0..1 : 64-row half
    const int wc   = wid & 1;       // 0..1 : 64-col half
    const int bx = blockIdx.x, by = blockIdx.y, b = blockIdx.z;
    const int r0 = bx * BM, c0 = by * BN;

    const __hip_bfloat16* A  = ptil + (size_t)b * NPAIR * LSEQ;
    const __hip_bfloat16* Bt = seqT + (size_t)b * DDIM * LSEQ;

    // staging indices: 256 threads, 64B (4 x uint4) each
    const int ar = t >> 1;            // A row 0..127
    const int ae = (t & 1) * 32;      // A elem offset
    const int bc = t >> 1;            // B col 0..127
    const int be = (t & 1) * 32;      // B elem offset

    const f32x4 zero = {0.f, 0.f, 0.f, 0.f};
    f32x4 acc[4][4];
    #pragma unroll
    for (int m = 0; m < 4; ++m)
        #pragma unroll
        for (int n = 0; n < 4; ++n) acc[m][n] = zero;

    const int fr = lane & 15, kg = lane >> 4;

    for (int k0 = 0; k0 < LSEQ; k0 += BK) {
        // ---- stage A (128 x 64 bf16) ----
        int gr = r0 + ar;
        if (gr < NPAIR) {
            const __hip_bfloat16* src = A + (size_t)gr * LSEQ + k0 + ae;
            uint4 r0v = *(const uint4*)(src +  0);
            uint4 r1v = *(const uint4*)(src +  8);
            uint4 r2v = *(const uint4*)(src + 16);
            uint4 r3v = *(const uint4*)(src + 24);
            *(uint4*)(&As[ar][ae +  0]) = r0v;
            *(uint4*)(&As[ar][ae +  8]) = r1v;
            *(uint4*)(&As[ar][ae + 16]) = r2v;
            *(uint4*)(&As[ar][ae + 24]) = r3v;
        } else {
            uint4 z = {0u, 0u, 0u, 0u};
            *(uint4*)(&As[ar][ae +  0]) = z;
            *(uint4*)(&As[ar][ae +  8]) = z;
            *(uint4*)(&As[ar][ae + 16]) = z;
            *(uint4*)(&As[ar][ae + 24]) = z;
        }
        // ---- stage B^T (128 cols x 64 k) ----
        {
            const __hip_bfloat16* src = Bt + (size_t)(c0 + bc) * LSEQ + k0 + be;
            uint4 b0v = *(const uint4*)(src +  0);
            uint4 b1v = *(const uint4*)(src +  8);
            uint4 b2v = *(const uint4*)(src + 16);
            uint4 b3v = *(const uint4*)(src + 24);
            *(uint4*)(&Bs[bc][be +  0]) = b0v;
            *(uint4*)(&Bs[bc][be +  8]) = b1v;
            *(uint4*)(&Bs[bc][be + 16]) = b2v;
            *(uint4*)(&Bs[bc][be + 24]) = b3v;
        }
        __syncthreads();

        // ---- MFMA: 2 K-chunks of 32, 4x4 fragments ----
        #pragma unroll
        for (int ks = 0; ks < 2; ++ks) {
            bf16x8 af[4], bfv[4];
            #pragma unroll
            for (int m = 0; m < 4; ++m)
                af[m] = *(const bf16x8*)(&As[wr*64 + m*16 + fr][ks*32 + kg*8]);
            #pragma unroll
            for (int n = 0; n < 4; ++n)
                bfv[n] = *(const bf16x8*)(&Bs[wc*64 + n*16 + fr][ks*32 + kg*8]);
            #pragma unroll
            for (int m = 0; m < 4; ++m)
                #pragma unroll
                for (int n = 0; n < 4; ++n)
                    acc[m][n] = __builtin_amdgcn_mfma_f32_16x16x32_bf16(
                                    af[m], bfv[n], acc[m][n], 0, 0, 0);
        }
        __syncthreads();
    }

    // ---- epilogue: scale by invS[row], store ----
    #pragma unroll
    for (int m = 0; m < 4; ++m) {
        int rb = r0 + wr*64 + m*16 + kg*4;
        #pragma unroll
        for (int i = 0; i < 4; ++i) {
            int row = rb + i;
            if (row < NPAIR) {
                float sc = invS[b*NPAIR + row];
                #pragma unroll
                for (int n = 0; n < 4; ++n) {
                    int col = c0 + wc*64 + n*16 + fr;
                    fmap[((size_t)b*NPAIR + row)*DDIM + col] = acc[m][n][i] * sc;
                }
            }
        }
    }
}

// ---------------- launcher ---------------------------------------------------
extern "C" void kernel_launch(void* const* d_in, const int* in_sizes, int n_in,
                              void* d_out, int out_size, void* d_ws, size_t ws_size,
                              hipStream_t stream) {
    const float* seq  = (const float*)d_in[0];
    const float* att  = (const float*)d_in[1];
    const int*   mpos = (const int*)d_in[2];
    const int*   ment = (const int*)d_in[3];
    const int*   hts  = (const int*)d_in[4];

    float* ws_f  = (float*)d_ws;
    float* e_emb = ws_f;
    float* e_att = ws_f + EMB_CNT;
    float* invS  = ws_f + EMB_CNT + EATT_CNT;
    __hip_bfloat16* ptil = (__hip_bfloat16*)(ws_f + FLOAT_CNT);
    __hip_bfloat16* seqT = ptil + PTIL_CNT;

    float* out_h = (float*)d_out;
    float* out_t = out_h + (size_t)BSZ*NPAIR*DDIM;
    float* fmap  = out_t + (size_t)BSZ*NPAIR*DDIM;

    hipLaunchKernelGGL(ent_emb_kernel, dim3(BSZ*NEN), dim3(256), 0, stream,
                       seq, mpos, ment, e_emb);
    hipLaunchKernelGGL(ent_att_kernel, dim3(BSZ*NEN*NH), dim3(256), 0, stream,
                       att, mpos, ment, e_att);
    hipLaunchKernelGGL(pair_sym_kernel, dim3(NTRI, BSZ), dim3(256), 0, stream,
                       e_att, ptil, invS);
    hipLaunchKernelGGL(gather_ht_kernel, dim3(BSZ*NPAIR), dim3(256), 0, stream,
                       e_emb, hts, out_h, out_t);
    hipLaunchKernelGGL(seq2bf16T_kernel, dim3(LSEQ/32, DDIM/32, BSZ),
                       dim3(256), 0, stream, seq, seqT);
    hipLaunchKernelGGL(fmap_mfma_kernel, dim3(MT, NT, BSZ),
                       dim3(256), 0, stream, ptil, seqT, invS, fmap);
}

// Round 5
// 117.601 us; speedup vs baseline: 1.2288x; 1.0310x over previous
//
#include <hip/hip_runtime.h>
#include <hip/hip_bf16.h>

#define BSZ   4
#define LSEQ  1024
#define NH    12
#define DDIM  768
#define NEN   42
#define NM    96
#define NPAIR (NEN*NEN)   /* 1764 */
#define NTRI  (NEN*(NEN+1)/2)  /* 903 */
#define OFF   1

typedef short bf16x8 __attribute__((ext_vector_type(8)));
typedef float f32x4  __attribute__((ext_vector_type(4)));

__device__ __forceinline__ float bf2f(unsigned short u) {
    union { unsigned u; float f; } c; c.u = ((unsigned)u) << 16; return c.f;
}

// ---------------- workspace layout ----------------
// f32: e_emb | invS   then bf16: e_att | ptil | seqT
#define EMB_CNT  (BSZ*NEN*DDIM)
#define INVS_CNT (BSZ*NPAIR)
#define EATT_CNT (BSZ*NEN*NH*LSEQ)
#define PTIL_CNT ((size_t)BSZ*NPAIR*LSEQ)

// ---------------- kernel 1: entity embeddings (segment logsumexp) -------------
__global__ void ent_emb_kernel(const float* __restrict__ seq,
                               const int* __restrict__ mpos,
                               const int* __restrict__ ment,
                               float* __restrict__ e_emb) {
    int b = blockIdx.x / NEN, e = blockIdx.x % NEN;
    __shared__ int sp[NM];
    __shared__ int se[NM];
    int t = threadIdx.x;
    if (t < NM) { sp[t] = mpos[b*NM + t] + OFF; se[t] = ment[b*NM + t]; }
    __syncthreads();
    const float* sq = seq + (size_t)b * LSEQ * DDIM;
    for (int d = t; d < DDIM; d += blockDim.x) {
        float mx = -1e30f; int cnt = 0;
        for (int m = 0; m < NM; ++m)
            if (se[m] == e) { ++cnt; mx = fmaxf(mx, sq[(size_t)sp[m]*DDIM + d]); }
        float out = 0.f;
        if (cnt) {
            float s = 0.f;
            for (int m = 0; m < NM; ++m)
                if (se[m] == e) s += expf(sq[(size_t)sp[m]*DDIM + d] - mx);
            out = logf(fmaxf(s, 1e-30f)) + mx;
        }
        e_emb[((size_t)b*NEN + e)*DDIM + d] = out;
    }
}

// ---------------- kernel 2: entity attentions (segment mean) -> bf16 ---------
__global__ void ent_att_kernel(const float* __restrict__ att,
                               const int* __restrict__ mpos,
                               const int* __restrict__ ment,
                               __hip_bfloat16* __restrict__ e_att) {
    int id = blockIdx.x;
    int h = id % NH;
    int e = (id / NH) % NEN;
    int b = id / (NH * NEN);
    __shared__ int sp[NM];
    __shared__ int se[NM];
    int t = threadIdx.x;
    if (t < NM) { sp[t] = mpos[b*NM + t] + OFF; se[t] = ment[b*NM + t]; }
    __syncthreads();
    const float* ab = att + ((size_t)(b*NH + h)) * LSEQ * LSEQ;
    float4 acc = {0.f, 0.f, 0.f, 0.f};
    int cnt = 0;
    for (int m = 0; m < NM; ++m) {
        if (se[m] == e) {
            ++cnt;
            float4 v = ((const float4*)(ab + (size_t)sp[m]*LSEQ))[t];
            acc.x += v.x; acc.y += v.y; acc.z += v.z; acc.w += v.w;
        }
    }
    float inv = cnt ? 1.f / (float)cnt : 0.f;
    union { ushort4 u4; __hip_bfloat16 hh[4]; } pk;
    pk.hh[0] = __float2bfloat16(acc.x * inv);
    pk.hh[1] = __float2bfloat16(acc.y * inv);
    pk.hh[2] = __float2bfloat16(acc.z * inv);
    pk.hh[3] = __float2bfloat16(acc.w * inv);
    ((ushort4*)(e_att + ((size_t)(b*NEN + e)*NH + h)*LSEQ))[t] = pk.u4;
}

// ---------------- kernel 3: symmetric pair products + invS (bf16 in) ---------
__global__ __launch_bounds__(256) void pair_sym_kernel(
        const __hip_bfloat16* __restrict__ e_att,
        __hip_bfloat16* __restrict__ ptil,
        float* __restrict__ invS) {
    int tri = blockIdx.x;          // 0..902
    int b   = blockIdx.y;
    int a = 0, rem = tri;
    while (rem >= NEN - a) { rem -= NEN - a; ++a; }   // uniform scalar loop
    int bb = a + rem;
    int t = threadIdx.x;           // 256 threads x 4 l = 1024 l
    const ushort4* ra = (const ushort4*)(e_att + ((size_t)(b*NEN + a )*NH)*LSEQ);
    const ushort4* rb = (const ushort4*)(e_att + ((size_t)(b*NEN + bb)*NH)*LSEQ);
    float4 acc = {0.f, 0.f, 0.f, 0.f};
    #pragma unroll
    for (int h = 0; h < NH; ++h) {
        ushort4 x = ra[h*(LSEQ/4) + t];
        ushort4 y = rb[h*(LSEQ/4) + t];
        acc.x += bf2f(x.x)*bf2f(y.x);
        acc.y += bf2f(x.y)*bf2f(y.y);
        acc.z += bf2f(x.z)*bf2f(y.z);
        acc.w += bf2f(x.w)*bf2f(y.w);
    }
    union { ushort4 u4; __hip_bfloat16 hh[4]; } pk;
    pk.hh[0] = __float2bfloat16(acc.x);
    pk.hh[1] = __float2bfloat16(acc.y);
    pk.hh[2] = __float2bfloat16(acc.z);
    pk.hh[3] = __float2bfloat16(acc.w);
    __hip_bfloat16* base = ptil + (size_t)b * NPAIR * LSEQ;
    *(ushort4*)(base + (size_t)(a*NEN + bb)*LSEQ + t*4) = pk.u4;
    if (a != bb)
        *(ushort4*)(base + (size_t)(bb*NEN + a)*LSEQ + t*4) = pk.u4;

    // block reduction of sum_l p  ->  invS = 1/(sum + H*1e-5)
    float s = acc.x + acc.y + acc.z + acc.w;
    #pragma unroll
    for (int o = 32; o > 0; o >>= 1) s += __shfl_down(s, o, 64);
    __shared__ float red[4];
    if ((t & 63) == 0) red[t >> 6] = s;
    __syncthreads();
    if (t == 0) {
        float tot = red[0] + red[1] + red[2] + red[3];
        float v = 1.f / (tot + (float)NH * 1e-5f);
        invS[b*NPAIR + a*NEN + bb] = v;
        if (a != bb) invS[b*NPAIR + bb*NEN + a] = v;
    }
}

// ---------------- kernel 4: gather hss / tss ---------------------------------
__global__ void gather_ht_kernel(const float* __restrict__ e_emb,
                                 const int* __restrict__ hts,
                                 float* __restrict__ out_h,
                                 float* __restrict__ out_t) {
    int id = blockIdx.x;                 // b*NPAIR + p
    int b  = id / NPAIR;
    int hi = hts[id*2 + 0];
    int ti = hts[id*2 + 1];
    const float4* eh = (const float4*)(e_emb + ((size_t)(b*NEN + hi))*DDIM);
    const float4* et = (const float4*)(e_emb + ((size_t)(b*NEN + ti))*DDIM);
    float4* oh = (float4*)(out_h + (size_t)id*DDIM);
    float4* ot = (float4*)(out_t + (size_t)id*DDIM);
    int t = threadIdx.x;
    if (t < DDIM/4) { oh[t] = eh[t]; ot[t] = et[t]; }
}

// ---------------- kernel 5: seq f32 [L][D] -> seqT bf16 [D][L] ---------------
__global__ void seq2bf16T_kernel(const float* __restrict__ seq,
                                 __hip_bfloat16* __restrict__ seqT) {
    int b  = blockIdx.z;
    int l0 = blockIdx.x * 32;
    int d0 = blockIdx.y * 32;
    __shared__ float tile[32][33];
    int t = threadIdx.x;
    int l = t >> 3, dq = (t & 7) * 4;
    float4 v = *(const float4*)(seq + ((size_t)b*LSEQ + l0 + l)*DDIM + d0 + dq);
    tile[l][dq+0] = v.x; tile[l][dq+1] = v.y; tile[l][dq+2] = v.z; tile[l][dq+3] = v.w;
    __syncthreads();
    int d = t >> 3, lq = (t & 7) * 4;
    union { ushort4 u4; __hip_bfloat16 h[4]; } pk;
    pk.h[0] = __float2bfloat16(tile[lq+0][d]);
    pk.h[1] = __float2bfloat16(tile[lq+1][d]);
    pk.h[2] = __float2bfloat16(tile[lq+2][d]);
    pk.h[3] = __float2bfloat16(tile[lq+3][d]);
    *(ushort4*)(seqT + ((size_t)b*DDIM + d0 + d)*LSEQ + l0 + lq) = pk.u4;
}

// ---------------- kernel 6: fmap GEMM (MFMA bf16)  C = (ptil @ seq) * invS ---
#define BM 128
#define BN 128
#define BK 64
#define MT 14           /* ceil(1764/128) */
#define NT (DDIM/BN)    /* 6 */

__global__ __launch_bounds__(256) void fmap_mfma_kernel(
        const __hip_bfloat16* __restrict__ ptil,
        const __hip_bfloat16* __restrict__ seqT,
        const float* __restrict__ invS,
        float* __restrict__ fmap) {
    __shared__ __hip_bfloat16 As[BM][BK + 8];   // 128 x 72
    __shared__ __hip_bfloat16 Bs[BN][BK + 8];   // 128 x 72 (col-major: Bs[col][k])

    const int t    = threadIdx.x;
    const int lane = t & 63;
    const int wid  = t >> 6;
    const int wr   = wid >> 1;      // 0..1 : 64-row half
    const int wc   = wid & 1;       // 0..1 : 64-col half
    const int bx = blockIdx.x, by = blockIdx.y, b = blockIdx.z;
    const int r0 = bx * BM, c0 = by * BN;

    const __hip_bfloat16* A  = ptil + (size_t)b * NPAIR * LSEQ;
    const __hip_bfloat16* Bt = seqT + (size_t)b * DDIM * LSEQ;

    // staging indices: 256 threads, 64B (4 x uint4) each
    const int ar = t >> 1;            // A row 0..127
    const int ae = (t & 1) * 32;      // A elem offset
    const int bc = t >> 1;            // B col 0..127
    const int be = (t & 1) * 32;      // B elem offset

    const f32x4 zero = {0.f, 0.f, 0.f, 0.f};
    f32x4 acc[4][4];
    #pragma unroll
    for (int m = 0; m < 4; ++m)
        #pragma unroll
        for (int n = 0; n < 4; ++n) acc[m][n] = zero;

    const int fr = lane & 15, kg = lane >> 4;

    for (int k0 = 0; k0 < LSEQ; k0 += BK) {
        // ---- stage A (128 x 64 bf16) ----
        int gr = r0 + ar;
        if (gr < NPAIR) {
            const __hip_bfloat16* src = A + (size_t)gr * LSEQ + k0 + ae;
            uint4 r0v = *(const uint4*)(src +  0);
            uint4 r1v = *(const uint4*)(src +  8);
            uint4 r2v = *(const uint4*)(src + 16);
            uint4 r3v = *(const uint4*)(src + 24);
            *(uint4*)(&As[ar][ae +  0]) = r0v;
            *(uint4*)(&As[ar][ae +  8]) = r1v;
            *(uint4*)(&As[ar][ae + 16]) = r2v;
            *(uint4*)(&As[ar][ae + 24]) = r3v;
        } else {
            uint4 z = {0u, 0u, 0u, 0u};
            *(uint4*)(&As[ar][ae +  0]) = z;
            *(uint4*)(&As[ar][ae +  8]) = z;
            *(uint4*)(&As[ar][ae + 16]) = z;
            *(uint4*)(&As[ar][ae + 24]) = z;
        }
        // ---- stage B^T (128 cols x 64 k) ----
        {
            const __hip_bfloat16* src = Bt + (size_t)(c0 + bc) * LSEQ + k0 + be;
            uint4 b0v = *(const uint4*)(src +  0);
            uint4 b1v = *(const uint4*)(src +  8);
            uint4 b2v = *(const uint4*)(src + 16);
            uint4 b3v = *(const uint4*)(src + 24);
            *(uint4*)(&Bs[bc][be +  0]) = b0v;
            *(uint4*)(&Bs[bc][be +  8]) = b1v;
            *(uint4*)(&Bs[bc][be + 16]) = b2v;
            *(uint4*)(&Bs[bc][be + 24]) = b3v;
        }
        __syncthreads();

        // ---- MFMA: 2 K-chunks of 32, 4x4 fragments ----
        #pragma unroll
        for (int ks = 0; ks < 2; ++ks) {
            bf16x8 af[4], bfv[4];
            #pragma unroll
            for (int m = 0; m < 4; ++m)
                af[m] = *(const bf16x8*)(&As[wr*64 + m*16 + fr][ks*32 + kg*8]);
            #pragma unroll
            for (int n = 0; n < 4; ++n)
                bfv[n] = *(const bf16x8*)(&Bs[wc*64 + n*16 + fr][ks*32 + kg*8]);
            #pragma unroll
            for (int m = 0; m < 4; ++m)
                #pragma unroll
                for (int n = 0; n < 4; ++n)
                    acc[m][n] = __builtin_amdgcn_mfma_f32_16x16x32_bf16(
                                    af[m], bfv[n], acc[m][n], 0, 0, 0);
        }
        __syncthreads();
    }

    // ---- epilogue: scale by invS[row], store ----
    #pragma unroll
    for (int m = 0; m < 4; ++m) {
        int rb = r0 + wr*64 + m*16 + kg*4;
        #pragma unroll
        for (int i = 0; i < 4; ++i) {
            int row = rb + i;
            if (row < NPAIR) {
                float sc = invS[b*NPAIR + row];
                #pragma unroll
                for (int n = 0; n < 4; ++n) {
                    int col = c0 + wc*64 + n*16 + fr;
                    fmap[((size_t)b*NPAIR + row)*DDIM + col] = acc[m][n][i] * sc;
                }
            }
        }
    }
}

// ---------------- launcher ---------------------------------------------------
extern "C" void kernel_launch(void* const* d_in, const int* in_sizes, int n_in,
                              void* d_out, int out_size, void* d_ws, size_t ws_size,
                              hipStream_t stream) {
    const float* seq  = (const float*)d_in[0];
    const float* att  = (const float*)d_in[1];
    const int*   mpos = (const int*)d_in[2];
    const int*   ment = (const int*)d_in[3];
    const int*   hts  = (const int*)d_in[4];

    float* ws_f  = (float*)d_ws;
    float* e_emb = ws_f;
    float* invS  = ws_f + EMB_CNT;
    __hip_bfloat16* e_att = (__hip_bfloat16*)(ws_f + EMB_CNT + INVS_CNT);
    __hip_bfloat16* ptil  = e_att + EATT_CNT;
    __hip_bfloat16* seqT  = ptil + PTIL_CNT;

    float* out_h = (float*)d_out;
    float* out_t = out_h + (size_t)BSZ*NPAIR*DDIM;
    float* fmap  = out_t + (size_t)BSZ*NPAIR*DDIM;

    hipLaunchKernelGGL(ent_emb_kernel, dim3(BSZ*NEN), dim3(256), 0, stream,
                       seq, mpos, ment, e_emb);
    hipLaunchKernelGGL(ent_att_kernel, dim3(BSZ*NEN*NH), dim3(256), 0, stream,
                       att, mpos, ment, e_att);
    hipLaunchKernelGGL(pair_sym_kernel, dim3(NTRI, BSZ), dim3(256), 0, stream,
                       e_att, ptil, invS);
    hipLaunchKernelGGL(gather_ht_kernel, dim3(BSZ*NPAIR), dim3(256), 0, stream,
                       e_emb, hts, out_h, out_t);
    hipLaunchKernelGGL(seq2bf16T_kernel, dim3(LSEQ/32, DDIM/32, BSZ),
                       dim3(256), 0, stream, seq, seqT);
    hipLaunchKernelGGL(fmap_mfma_kernel, dim3(MT, NT, BSZ),
                       dim3(256), 0, stream, ptil, seqT, invS, fmap);
}

// Round 6
// 111.628 us; speedup vs baseline: 1.2945x; 1.0535x over previous
//
#include <hip/hip_runtime.h>
#include <hip/hip_bf16.h>

#define BSZ   4
#define LSEQ  1024
#define NH    12
#define DDIM  768
#define NEN   42
#define NM    96
#define NPAIR (NEN*NEN)   /* 1764 */
#define NTRI  (NEN*(NEN+1)/2)  /* 903 */
#define OFF   1

typedef short bf16x8 __attribute__((ext_vector_type(8)));
typedef float f32x4  __attribute__((ext_vector_type(4)));

__device__ __forceinline__ float bf2f(unsigned short u) {
    union { unsigned u; float f; } c; c.u = ((unsigned)u) << 16; return c.f;
}

// ---------------- workspace layout ----------------
// f32: e_emb | invS   then bf16: e_att | ptil | seqT
#define EMB_CNT  (BSZ*NEN*DDIM)
#define INVS_CNT (BSZ*NPAIR)
#define EATT_CNT (BSZ*NEN*NH*LSEQ)
#define PTIL_CNT ((size_t)BSZ*NPAIR*LSEQ)

// grid partition for prep_kernel (heavier first)
#define PREP_ATT_BLKS  (BSZ*NEN*NH)          /* 2016 */
#define PREP_T_BLKS    ((LSEQ/32)*(DDIM/32)*BSZ)  /* 3072 */
#define PREP_EMB_BLKS  (BSZ*NEN)             /* 168 */
#define PREP_TOTAL     (PREP_ATT_BLKS + PREP_T_BLKS + PREP_EMB_BLKS)

// grid partition for mid_kernel
#define MID_PAIR_BLKS  (NTRI*BSZ)            /* 3612 */
#define MID_GATH_BLKS  (BSZ*NPAIR)           /* 7056 */
#define MID_TOTAL      (MID_PAIR_BLKS + MID_GATH_BLKS)

// ================= kernel 1: fused prep (ent_att | seq2bf16T | ent_emb) ======
__global__ __launch_bounds__(256) void prep_kernel(
        const float* __restrict__ seq,
        const float* __restrict__ att,
        const int* __restrict__ mpos,
        const int* __restrict__ ment,
        float* __restrict__ e_emb,
        __hip_bfloat16* __restrict__ e_att,
        __hip_bfloat16* __restrict__ seqT) {
    __shared__ __align__(16) char smraw[4352];
    const int bid = blockIdx.x;
    const int t = threadIdx.x;

    if (bid < PREP_ATT_BLKS) {
        // ---------- ent_att: segment-mean of attention rows -> bf16 ----------
        int id = bid;
        int h = id % NH;
        int e = (id / NH) % NEN;
        int b = id / (NH * NEN);
        int* sp = (int*)smraw;
        int* se = sp + NM;
        if (t < NM) { sp[t] = mpos[b*NM + t] + OFF; se[t] = ment[b*NM + t]; }
        __syncthreads();
        const float* ab = att + ((size_t)(b*NH + h)) * LSEQ * LSEQ;
        float4 acc = {0.f, 0.f, 0.f, 0.f};
        int cnt = 0;
        for (int m = 0; m < NM; ++m) {
            if (se[m] == e) {
                ++cnt;
                float4 v = ((const float4*)(ab + (size_t)sp[m]*LSEQ))[t];
                acc.x += v.x; acc.y += v.y; acc.z += v.z; acc.w += v.w;
            }
        }
        float inv = cnt ? 1.f / (float)cnt : 0.f;
        union { ushort4 u4; __hip_bfloat16 hh[4]; } pk;
        pk.hh[0] = __float2bfloat16(acc.x * inv);
        pk.hh[1] = __float2bfloat16(acc.y * inv);
        pk.hh[2] = __float2bfloat16(acc.z * inv);
        pk.hh[3] = __float2bfloat16(acc.w * inv);
        ((ushort4*)(e_att + ((size_t)(b*NEN + e)*NH + h)*LSEQ))[t] = pk.u4;
    } else if (bid < PREP_ATT_BLKS + PREP_T_BLKS) {
        // ---------- seq2bf16T: seq f32 [L][D] -> seqT bf16 [D][L] ------------
        int id = bid - PREP_ATT_BLKS;
        int l0 = (id % (LSEQ/32)) * 32;
        int d0 = ((id / (LSEQ/32)) % (DDIM/32)) * 32;
        int b  = id / ((LSEQ/32) * (DDIM/32));
        float (*tile)[33] = (float(*)[33])smraw;
        int l = t >> 3, dq = (t & 7) * 4;
        float4 v = *(const float4*)(seq + ((size_t)b*LSEQ + l0 + l)*DDIM + d0 + dq);
        tile[l][dq+0] = v.x; tile[l][dq+1] = v.y;
        tile[l][dq+2] = v.z; tile[l][dq+3] = v.w;
        __syncthreads();
        int d = t >> 3, lq = (t & 7) * 4;
        union { ushort4 u4; __hip_bfloat16 h[4]; } pk;
        pk.h[0] = __float2bfloat16(tile[lq+0][d]);
        pk.h[1] = __float2bfloat16(tile[lq+1][d]);
        pk.h[2] = __float2bfloat16(tile[lq+2][d]);
        pk.h[3] = __float2bfloat16(tile[lq+3][d]);
        *(ushort4*)(seqT + ((size_t)b*DDIM + d0 + d)*LSEQ + l0 + lq) = pk.u4;
    } else {
        // ---------- ent_emb: segment logsumexp of mention embeddings ---------
        int id = bid - PREP_ATT_BLKS - PREP_T_BLKS;
        int b = id / NEN, e = id % NEN;
        int* sp = (int*)smraw;
        int* se = sp + NM;
        if (t < NM) { sp[t] = mpos[b*NM + t] + OFF; se[t] = ment[b*NM + t]; }
        __syncthreads();
        const float* sq = seq + (size_t)b * LSEQ * DDIM;
        for (int d = t; d < DDIM; d += 256) {
            float mx = -1e30f; int cnt = 0;
            for (int m = 0; m < NM; ++m)
                if (se[m] == e) { ++cnt; mx = fmaxf(mx, sq[(size_t)sp[m]*DDIM + d]); }
            float out = 0.f;
            if (cnt) {
                float s = 0.f;
                for (int m = 0; m < NM; ++m)
                    if (se[m] == e) s += expf(sq[(size_t)sp[m]*DDIM + d] - mx);
                out = logf(fmaxf(s, 1e-30f)) + mx;
            }
            e_emb[((size_t)b*NEN + e)*DDIM + d] = out;
        }
    }
}

// ================= kernel 2: fused mid (pair_sym | gather_ht) ================
__global__ __launch_bounds__(256) void mid_kernel(
        const __hip_bfloat16* __restrict__ e_att,
        const float* __restrict__ e_emb,
        const int* __restrict__ hts,
        __hip_bfloat16* __restrict__ ptil,
        float* __restrict__ invS,
        float* __restrict__ out_h,
        float* __restrict__ out_t) {
    const int bid = blockIdx.x;
    const int t = threadIdx.x;

    if (bid < MID_PAIR_BLKS) {
        // ---------- pair_sym: p~[a,b,l] bf16 + invS --------------------------
        int tri = bid % NTRI;
        int b   = bid / NTRI;
        int a = 0, rem = tri;
        while (rem >= NEN - a) { rem -= NEN - a; ++a; }
        int bb = a + rem;
        const ushort4* ra = (const ushort4*)(e_att + ((size_t)(b*NEN + a )*NH)*LSEQ);
        const ushort4* rb = (const ushort4*)(e_att + ((size_t)(b*NEN + bb)*NH)*LSEQ);
        float4 acc = {0.f, 0.f, 0.f, 0.f};
        #pragma unroll
        for (int h = 0; h < NH; ++h) {
            ushort4 x = ra[h*(LSEQ/4) + t];
            ushort4 y = rb[h*(LSEQ/4) + t];
            acc.x += bf2f(x.x)*bf2f(y.x);
            acc.y += bf2f(x.y)*bf2f(y.y);
            acc.z += bf2f(x.z)*bf2f(y.z);
            acc.w += bf2f(x.w)*bf2f(y.w);
        }
        union { ushort4 u4; __hip_bfloat16 hh[4]; } pk;
        pk.hh[0] = __float2bfloat16(acc.x);
        pk.hh[1] = __float2bfloat16(acc.y);
        pk.hh[2] = __float2bfloat16(acc.z);
        pk.hh[3] = __float2bfloat16(acc.w);
        __hip_bfloat16* base = ptil + (size_t)b * NPAIR * LSEQ;
        *(ushort4*)(base + (size_t)(a*NEN + bb)*LSEQ + t*4) = pk.u4;
        if (a != bb)
            *(ushort4*)(base + (size_t)(bb*NEN + a)*LSEQ + t*4) = pk.u4;

        float s = acc.x + acc.y + acc.z + acc.w;
        #pragma unroll
        for (int o = 32; o > 0; o >>= 1) s += __shfl_down(s, o, 64);
        __shared__ float red[4];
        if ((t & 63) == 0) red[t >> 6] = s;
        __syncthreads();
        if (t == 0) {
            float tot = red[0] + red[1] + red[2] + red[3];
            float v = 1.f / (tot + (float)NH * 1e-5f);
            invS[b*NPAIR + a*NEN + bb] = v;
            if (a != bb) invS[b*NPAIR + bb*NEN + a] = v;
        }
    } else {
        // ---------- gather hss / tss ----------------------------------------
        int id = bid - MID_PAIR_BLKS;        // b*NPAIR + p
        int b  = id / NPAIR;
        int hi = hts[id*2 + 0];
        int ti = hts[id*2 + 1];
        const float4* eh = (const float4*)(e_emb + ((size_t)(b*NEN + hi))*DDIM);
        const float4* et = (const float4*)(e_emb + ((size_t)(b*NEN + ti))*DDIM);
        float4* oh = (float4*)(out_h + (size_t)id*DDIM);
        float4* ot = (float4*)(out_t + (size_t)id*DDIM);
        if (t < DDIM/4) { oh[t] = eh[t]; ot[t] = et[t]; }
    }
}

// ================= kernel 3: fmap GEMM (MFMA bf16)  C = (ptil @ seq)*invS ====
#define BM 128
#define BN 128
#define BK 64
#define MT 14           /* ceil(1764/128) */
#define NT (DDIM/BN)    /* 6 */

__global__ __launch_bounds__(256) void fmap_mfma_kernel(
        const __hip_bfloat16* __restrict__ ptil,
        const __hip_bfloat16* __restrict__ seqT,
        const float* __restrict__ invS,
        float* __restrict__ fmap) {
    __shared__ __hip_bfloat16 As[BM][BK + 8];   // 128 x 72
    __shared__ __hip_bfloat16 Bs[BN][BK + 8];   // 128 x 72 (col-major: Bs[col][k])

    const int t    = threadIdx.x;
    const int lane = t & 63;
    const int wid  = t >> 6;
    const int wr   = wid >> 1;      // 0..1 : 64-row half
    const int wc   = wid & 1;       // 0..1 : 64-col half
    const int bx = blockIdx.x, by = blockIdx.y, b = blockIdx.z;
    const int r0 = bx * BM, c0 = by * BN;

    const __hip_bfloat16* A  = ptil + (size_t)b * NPAIR * LSEQ;
    const __hip_bfloat16* Bt = seqT + (size_t)b * DDIM * LSEQ;

    const int ar = t >> 1;            // A row 0..127
    const int ae = (t & 1) * 32;      // A elem offset
    const int bc = t >> 1;            // B col 0..127
    const int be = (t & 1) * 32;      // B elem offset

    const f32x4 zero = {0.f, 0.f, 0.f, 0.f};
    f32x4 acc[4][4];
    #pragma unroll
    for (int m = 0; m < 4; ++m)
        #pragma unroll
        for (int n = 0; n < 4; ++n) acc[m][n] = zero;

    const int fr = lane & 15, kg = lane >> 4;

    for (int k0 = 0; k0 < LSEQ; k0 += BK) {
        int gr = r0 + ar;
        if (gr < NPAIR) {
            const __hip_bfloat16* src = A + (size_t)gr * LSEQ + k0 + ae;
            uint4 r0v = *(const uint4*)(src +  0);
            uint4 r1v = *(const uint4*)(src +  8);
            uint4 r2v = *(const uint4*)(src + 16);
            uint4 r3v = *(const uint4*)(src + 24);
            *(uint4*)(&As[ar][ae +  0]) = r0v;
            *(uint4*)(&As[ar][ae +  8]) = r1v;
            *(uint4*)(&As[ar][ae + 16]) = r2v;
            *(uint4*)(&As[ar][ae + 24]) = r3v;
        } else {
            uint4 z = {0u, 0u, 0u, 0u};
            *(uint4*)(&As[ar][ae +  0]) = z;
            *(uint4*)(&As[ar][ae +  8]) = z;
            *(uint4*)(&As[ar][ae + 16]) = z;
            *(uint4*)(&As[ar][ae + 24]) = z;
        }
        {
            const __hip_bfloat16* src = Bt + (size_t)(c0 + bc) * LSEQ + k0 + be;
            uint4 b0v = *(const uint4*)(src +  0);
            uint4 b1v = *(const uint4*)(src +  8);
            uint4 b2v = *(const uint4*)(src + 16);
            uint4 b3v = *(const uint4*)(src + 24);
            *(uint4*)(&Bs[bc][be +  0]) = b0v;
            *(uint4*)(&Bs[bc][be +  8]) = b1v;
            *(uint4*)(&Bs[bc][be + 16]) = b2v;
            *(uint4*)(&Bs[bc][be + 24]) = b3v;
        }
        __syncthreads();

        #pragma unroll
        for (int ks = 0; ks < 2; ++ks) {
            bf16x8 af[4], bfv[4];
            #pragma unroll
            for (int m = 0; m < 4; ++m)
                af[m] = *(const bf16x8*)(&As[wr*64 + m*16 + fr][ks*32 + kg*8]);
            #pragma unroll
            for (int n = 0; n < 4; ++n)
                bfv[n] = *(const bf16x8*)(&Bs[wc*64 + n*16 + fr][ks*32 + kg*8]);
            #pragma unroll
            for (int m = 0; m < 4; ++m)
                #pragma unroll
                for (int n = 0; n < 4; ++n)
                    acc[m][n] = __builtin_amdgcn_mfma_f32_16x16x32_bf16(
                                    af[m], bfv[n], acc[m][n], 0, 0, 0);
        }
        __syncthreads();
    }

    #pragma unroll
    for (int m = 0; m < 4; ++m) {
        int rb = r0 + wr*64 + m*16 + kg*4;
        #pragma unroll
        for (int i = 0; i < 4; ++i) {
            int row = rb + i;
            if (row < NPAIR) {
                float sc = invS[b*NPAIR + row];
                #pragma unroll
                for (int n = 0; n < 4; ++n) {
                    int col = c0 + wc*64 + n*16 + fr;
                    fmap[((size_t)b*NPAIR + row)*DDIM + col] = acc[m][n][i] * sc;
                }
            }
        }
    }
}

// ---------------- launcher ---------------------------------------------------
extern "C" void kernel_launch(void* const* d_in, const int* in_sizes, int n_in,
                              void* d_out, int out_size, void* d_ws, size_t ws_size,
                              hipStream_t stream) {
    const float* seq  = (const float*)d_in[0];
    const float* att  = (const float*)d_in[1];
    const int*   mpos = (const int*)d_in[2];
    const int*   ment = (const int*)d_in[3];
    const int*   hts  = (const int*)d_in[4];

    float* ws_f  = (float*)d_ws;
    float* e_emb = ws_f;
    float* invS  = ws_f + EMB_CNT;
    __hip_bfloat16* e_att = (__hip_bfloat16*)(ws_f + EMB_CNT + INVS_CNT);
    __hip_bfloat16* ptil  = e_att + EATT_CNT;
    __hip_bfloat16* seqT  = ptil + PTIL_CNT;

    float* out_h = (float*)d_out;
    float* out_t = out_h + (size_t)BSZ*NPAIR*DDIM;
    float* fmap  = out_t + (size_t)BSZ*NPAIR*DDIM;

    hipLaunchKernelGGL(prep_kernel, dim3(PREP_TOTAL), dim3(256), 0, stream,
                       seq, att, mpos, ment, e_emb, e_att, seqT);
    hipLaunchKernelGGL(mid_kernel, dim3(MID_TOTAL), dim3(256), 0, stream,
                       e_att, e_emb, hts, ptil, invS, out_h, out_t);
    hipLaunchKernelGGL(fmap_mfma_kernel, dim3(MT, NT, BSZ),
                       dim3(256), 0, stream, ptil, seqT, invS, fmap);
}

// Round 7
// 69.198 us; speedup vs baseline: 2.0883x; 1.6132x over previous
//
#include <hip/hip_runtime.h>
#include <hip/hip_bf16.h>

#define BSZ   4
#define LSEQ  1024
#define NH    12
#define DDIM  768
#define NEN   42
#define NM    96
#define NPAIR (NEN*NEN)   /* 1764 */
#define OFF   1

typedef short bf16x8 __attribute__((ext_vector_type(8)));
typedef float f32x4  __attribute__((ext_vector_type(4)));

__device__ __forceinline__ float bf2f(unsigned short u) {
    union { unsigned u; float f; } c; c.u = ((unsigned)u) << 16; return c.f;
}

typedef const __attribute__((address_space(1))) unsigned int glb_u32;
typedef __attribute__((address_space(3))) unsigned int lds_u32;
__device__ __forceinline__ void glds16(const void* g, void* l) {
    __builtin_amdgcn_global_load_lds((glb_u32*)g, (lds_u32*)l, 16, 0, 0);
}

// ---------------- workspace layout ----------------
// f32: e_emb | invS   then bf16: e_att | ptil | seqT
#define EMB_CNT  (BSZ*NEN*DDIM)
#define INVS_CNT (BSZ*NPAIR)
#define EATT_CNT (BSZ*NEN*NH*LSEQ)
#define PTIL_CNT ((size_t)BSZ*NPAIR*LSEQ)

// prep grid: ent_emb (first: longest latency) | ent_att | seq transpose
#define PREP_EMB_BLKS  (BSZ*NEN*3)                 /* 504  */
#define PREP_ATT_BLKS  (BSZ*NEN*NH)                /* 2016 */
#define PREP_T_BLKS    ((LSEQ/32)*(DDIM/32)*BSZ)   /* 3072 */
#define PREP_TOTAL     (PREP_EMB_BLKS + PREP_ATT_BLKS + PREP_T_BLKS)

// mid grid: pair (a x 6-partner groups) | gather (4 pairs/block)
#define GRP 6
#define NGRP 7                                     /* ceil(42/6) */
#define MID_PAIR_BLKS  (NEN*NGRP*BSZ)              /* 1176 */
#define MID_GATH_BLKS  (BSZ*NPAIR/4)               /* 1764 */
#define MID_TOTAL      (MID_PAIR_BLKS + MID_GATH_BLKS)

// ================= kernel 1: fused prep ======================================
__global__ __launch_bounds__(256) void prep_kernel(
        const float* __restrict__ seq,
        const float* __restrict__ att,
        const int* __restrict__ mpos,
        const int* __restrict__ ment,
        float* __restrict__ e_emb,
        __hip_bfloat16* __restrict__ e_att,
        __hip_bfloat16* __restrict__ seqT) {
    __shared__ __align__(16) char smraw[4352];
    const int bid = blockIdx.x;
    const int t = threadIdx.x;

    if (bid < PREP_EMB_BLKS) {
        // ---------- ent_emb: segment logsumexp, one 256-d chunk per block ----
        int chunk = bid % 3;
        int e = (bid / 3) % NEN;
        int b = bid / (3 * NEN);
        int* sp   = (int*)smraw;
        int* se   = sp + NM;
        int* list = se + NM;
        int* pcnt = list + NM;
        if (t < NM) { sp[t] = mpos[b*NM + t] + OFF; se[t] = ment[b*NM + t]; }
        __syncthreads();
        if (t == 0) {                       // deterministic compaction
            int c = 0;
            for (int m = 0; m < NM; ++m) if (se[m] == e) list[c++] = sp[m];
            pcnt[0] = c;
        }
        __syncthreads();
        int cnt = pcnt[0];
        int d = chunk * 256 + t;
        const float* sq = seq + (size_t)b * LSEQ * DDIM + d;
        float mx = -1e30f;
        for (int m = 0; m < cnt; ++m) mx = fmaxf(mx, sq[(size_t)list[m] * DDIM]);
        float out = 0.f;
        if (cnt) {
            float s = 0.f;
            for (int m = 0; m < cnt; ++m) s += expf(sq[(size_t)list[m] * DDIM] - mx);
            out = logf(fmaxf(s, 1e-30f)) + mx;
        }
        e_emb[((size_t)b*NEN + e)*DDIM + d] = out;
    } else if (bid < PREP_EMB_BLKS + PREP_ATT_BLKS) {
        // ---------- ent_att: segment-mean of attention rows -> bf16 ----------
        int id = bid - PREP_EMB_BLKS;
        int h = id % NH;
        int e = (id / NH) % NEN;
        int b = id / (NH * NEN);
        int* sp = (int*)smraw;
        int* se = sp + NM;
        if (t < NM) { sp[t] = mpos[b*NM + t] + OFF; se[t] = ment[b*NM + t]; }
        __syncthreads();
        const float* ab = att + ((size_t)(b*NH + h)) * LSEQ * LSEQ;
        float4 acc = {0.f, 0.f, 0.f, 0.f};
        int cnt = 0;
        for (int m = 0; m < NM; ++m) {
            if (se[m] == e) {
                ++cnt;
                float4 v = ((const float4*)(ab + (size_t)sp[m]*LSEQ))[t];
                acc.x += v.x; acc.y += v.y; acc.z += v.z; acc.w += v.w;
            }
        }
        float inv = cnt ? 1.f / (float)cnt : 0.f;
        union { ushort4 u4; __hip_bfloat16 hh[4]; } pk;
        pk.hh[0] = __float2bfloat16(acc.x * inv);
        pk.hh[1] = __float2bfloat16(acc.y * inv);
        pk.hh[2] = __float2bfloat16(acc.z * inv);
        pk.hh[3] = __float2bfloat16(acc.w * inv);
        ((ushort4*)(e_att + ((size_t)(b*NEN + e)*NH + h)*LSEQ))[t] = pk.u4;
    } else {
        // ---------- seq2bf16T: seq f32 [L][D] -> seqT bf16 [D][L] ------------
        int id = bid - PREP_EMB_BLKS - PREP_ATT_BLKS;
        int l0 = (id % (LSEQ/32)) * 32;
        int d0 = ((id / (LSEQ/32)) % (DDIM/32)) * 32;
        int b  = id / ((LSEQ/32) * (DDIM/32));
        float (*tile)[33] = (float(*)[33])smraw;
        int l = t >> 3, dq = (t & 7) * 4;
        float4 v = *(const float4*)(seq + ((size_t)b*LSEQ + l0 + l)*DDIM + d0 + dq);
        tile[l][dq+0] = v.x; tile[l][dq+1] = v.y;
        tile[l][dq+2] = v.z; tile[l][dq+3] = v.w;
        __syncthreads();
        int d = t >> 3, lq = (t & 7) * 4;
        union { ushort4 u4; __hip_bfloat16 h[4]; } pk;
        pk.h[0] = __float2bfloat16(tile[lq+0][d]);
        pk.h[1] = __float2bfloat16(tile[lq+1][d]);
        pk.h[2] = __float2bfloat16(tile[lq+2][d]);
        pk.h[3] = __float2bfloat16(tile[lq+3][d]);
        *(ushort4*)(seqT + ((size_t)b*DDIM + d0 + d)*LSEQ + l0 + lq) = pk.u4;
    }
}

// ================= kernel 2: fused mid (pair groups | gather) ================
__global__ __launch_bounds__(256) void mid_kernel(
        const __hip_bfloat16* __restrict__ e_att,
        const float* __restrict__ e_emb,
        const int* __restrict__ hts,
        __hip_bfloat16* __restrict__ ptil,
        float* __restrict__ invS,
        float* __restrict__ out_h,
        float* __restrict__ out_t) {
    const int bid = blockIdx.x;
    const int t = threadIdx.x;

    if (bid < MID_PAIR_BLKS) {
        // ---------- pair: a-row in regs, 6 partners per block ----------------
        int cell = bid;
        int b  = cell / (NEN * NGRP);
        int rc = cell % (NEN * NGRP);
        int a  = rc / NGRP;
        int g  = rc % NGRP;
        int bb0 = a + g * GRP;
        if (bb0 >= NEN) return;                 // whole block exits
        int nb = min(GRP, NEN - bb0);
        const ushort4* ra = (const ushort4*)(e_att + ((size_t)(b*NEN + a)*NH)*LSEQ);
        float4 xa[NH];
        #pragma unroll
        for (int h = 0; h < NH; ++h) {
            ushort4 u = ra[h*(LSEQ/4) + t];
            xa[h].x = bf2f(u.x); xa[h].y = bf2f(u.y);
            xa[h].z = bf2f(u.z); xa[h].w = bf2f(u.w);
        }
        __hip_bfloat16* base = ptil + (size_t)b * NPAIR * LSEQ;
        __shared__ float red[4];
        for (int j = 0; j < nb; ++j) {
            int bb = bb0 + j;
            const ushort4* rb = (const ushort4*)(e_att + ((size_t)(b*NEN + bb)*NH)*LSEQ);
            float4 acc = {0.f, 0.f, 0.f, 0.f};
            #pragma unroll
            for (int h = 0; h < NH; ++h) {
                ushort4 y = rb[h*(LSEQ/4) + t];
                acc.x += xa[h].x * bf2f(y.x);
                acc.y += xa[h].y * bf2f(y.y);
                acc.z += xa[h].z * bf2f(y.z);
                acc.w += xa[h].w * bf2f(y.w);
            }
            union { ushort4 u4; __hip_bfloat16 hh[4]; } pk;
            pk.hh[0] = __float2bfloat16(acc.x);
            pk.hh[1] = __float2bfloat16(acc.y);
            pk.hh[2] = __float2bfloat16(acc.z);
            pk.hh[3] = __float2bfloat16(acc.w);
            *(ushort4*)(base + (size_t)(a*NEN + bb)*LSEQ + t*4) = pk.u4;
            if (bb != a)
                *(ushort4*)(base + (size_t)(bb*NEN + a)*LSEQ + t*4) = pk.u4;

            float s = acc.x + acc.y + acc.z + acc.w;
            #pragma unroll
            for (int o = 32; o > 0; o >>= 1) s += __shfl_down(s, o, 64);
            if ((t & 63) == 0) red[t >> 6] = s;
            __syncthreads();
            if (t == 0) {
                float tot = red[0] + red[1] + red[2] + red[3];
                float v = 1.f / (tot + (float)NH * 1e-5f);
                invS[b*NPAIR + a*NEN + bb] = v;
                if (bb != a) invS[b*NPAIR + bb*NEN + a] = v;
            }
            __syncthreads();
        }
    } else {
        // ---------- gather hss / tss: 4 pairs per block ----------------------
        int id4  = bid - MID_PAIR_BLKS;          // 0..1763
        int grp  = t >> 6;
        int lane = t & 63;
        int id   = id4 * 4 + grp;                // b*NPAIR + p
        int b    = id / NPAIR;
        int hi = hts[id*2 + 0];
        int ti = hts[id*2 + 1];
        const float4* eh = (const float4*)(e_emb + ((size_t)(b*NEN + hi))*DDIM);
        const float4* et = (const float4*)(e_emb + ((size_t)(b*NEN + ti))*DDIM);
        float4* oh = (float4*)(out_h + (size_t)id*DDIM);
        float4* ot = (float4*)(out_t + (size_t)id*DDIM);
        #pragma unroll
        for (int i = 0; i < 3; ++i) {            // 192 float4 per row
            oh[lane + 64*i] = eh[lane + 64*i];
            ot[lane + 64*i] = et[lane + 64*i];
        }
    }
}

// ================= kernel 3: fmap GEMM (glds + XOR swizzle) ==================
#define BM 128
#define BN 64
#define BK 64
#define MT 14           /* ceil(1764/128) */
#define NT (DDIM/BN)    /* 12 */

__global__ __launch_bounds__(256) void fmap_mfma_kernel(
        const __hip_bfloat16* __restrict__ ptil,
        const __hip_bfloat16* __restrict__ seqT,
        const float* __restrict__ invS,
        float* __restrict__ fmap) {
    __shared__ __hip_bfloat16 As[BM * BK];      // linear, 16 KB, XOR-swizzled
    __shared__ __hip_bfloat16 Bs[BN * BK];      // linear,  8 KB, XOR-swizzled

    const int t    = threadIdx.x;
    const int lane = t & 63;
    const int wid  = t >> 6;
    const int wr   = wid >> 1;      // 0..1 : 64-row half
    const int wc   = wid & 1;       // 0..1 : 32-col half
    const int bx = blockIdx.x, by = blockIdx.y, b = blockIdx.z;
    const int r0 = bx * BM, c0 = by * BN;

    const char* A  = (const char*)(ptil + (size_t)b * NPAIR * LSEQ);
    const char* Bt = (const char*)(seqT + (size_t)b * DDIM * LSEQ);
    char* AsB = (char*)As;
    char* BsB = (char*)Bs;

    const f32x4 zero = {0.f, 0.f, 0.f, 0.f};
    f32x4 acc[4][2];
    #pragma unroll
    for (int m = 0; m < 4; ++m)
        #pragma unroll
        for (int n = 0; n < 2; ++n) acc[m][n] = zero;

    const int fr = lane & 15, kg = lane >> 4;

    for (int k0 = 0; k0 < LSEQ; k0 += BK) {
        // ---- stage A: 128 rows x 128 B, glds, source pre-swizzled ----
        #pragma unroll
        for (int i = 0; i < 4; ++i) {
            int L = wid*4096 + i*1024 + lane*16;
            int r = L >> 7, beta = L & 127;
            const char* src = A + (size_t)(r0 + r)*(LSEQ*2) + k0*2
                                + (beta ^ ((r & 7) << 4));
            glds16(src, AsB + wid*4096 + i*1024);
        }
        // ---- stage B: 64 cols x 128 B ----
        #pragma unroll
        for (int i = 0; i < 2; ++i) {
            int L = wid*2048 + i*1024 + lane*16;
            int c = L >> 7, beta = L & 127;
            const char* src = Bt + (size_t)(c0 + c)*(LSEQ*2) + k0*2
                                + (beta ^ ((c & 7) << 4));
            glds16(src, BsB + wid*2048 + i*1024);
        }
        __syncthreads();    // drains vmcnt

        #pragma unroll
        for (int ks = 0; ks < 2; ++ks) {
            bf16x8 af[4], bfv[2];
            #pragma unroll
            for (int m = 0; m < 4; ++m) {
                int R = wr*64 + m*16 + fr;
                int e0 = (ks*32 + kg*8) ^ ((R & 7) << 3);
                af[m] = *(const bf16x8*)(As + R*64 + e0);
            }
            #pragma unroll
            for (int n = 0; n < 2; ++n) {
                int C = wc*32 + n*16 + fr;
                int e0 = (ks*32 + kg*8) ^ ((C & 7) << 3);
                bfv[n] = *(const bf16x8*)(Bs + C*64 + e0);
            }
            #pragma unroll
            for (int m = 0; m < 4; ++m)
                #pragma unroll
                for (int n = 0; n < 2; ++n)
                    acc[m][n] = __builtin_amdgcn_mfma_f32_16x16x32_bf16(
                                    af[m], bfv[n], acc[m][n], 0, 0, 0);
        }
        __syncthreads();
    }

    #pragma unroll
    for (int m = 0; m < 4; ++m) {
        int rb = r0 + wr*64 + m*16 + kg*4;
        #pragma unroll
        for (int i = 0; i < 4; ++i) {
            int row = rb + i;
            if (row < NPAIR) {
                float sc = invS[b*NPAIR + row];
                #pragma unroll
                for (int n = 0; n < 2; ++n) {
                    int col = c0 + wc*32 + n*16 + fr;
                    fmap[((size_t)b*NPAIR + row)*DDIM + col] = acc[m][n][i] * sc;
                }
            }
        }
    }
}

// ---------------- launcher ---------------------------------------------------
extern "C" void kernel_launch(void* const* d_in, const int* in_sizes, int n_in,
                              void* d_out, int out_size, void* d_ws, size_t ws_size,
                              hipStream_t stream) {
    const float* seq  = (const float*)d_in[0];
    const float* att  = (const float*)d_in[1];
    const int*   mpos = (const int*)d_in[2];
    const int*   ment = (const int*)d_in[3];
    const int*   hts  = (const int*)d_in[4];

    float* ws_f  = (float*)d_ws;
    float* e_emb = ws_f;
    float* invS  = ws_f + EMB_CNT;
    __hip_bfloat16* e_att = (__hip_bfloat16*)(ws_f + EMB_CNT + INVS_CNT);
    __hip_bfloat16* ptil  = e_att + EATT_CNT;
    __hip_bfloat16* seqT  = ptil + PTIL_CNT;

    float* out_h = (float*)d_out;
    float* out_t = out_h + (size_t)BSZ*NPAIR*DDIM;
    float* fmap  = out_t + (size_t)BSZ*NPAIR*DDIM;

    hipLaunchKernelGGL(prep_kernel, dim3(PREP_TOTAL), dim3(256), 0, stream,
                       seq, att, mpos, ment, e_emb, e_att, seqT);
    hipLaunchKernelGGL(mid_kernel, dim3(MID_TOTAL), dim3(256), 0, stream,
                       e_att, e_emb, hts, ptil, invS, out_h, out_t);
    hipLaunchKernelGGL(fmap_mfma_kernel, dim3(MT, NT, BSZ),
                       dim3(256), 0, stream, ptil, seqT, invS, fmap);
}

// Round 8
// 59.733 us; speedup vs baseline: 2.4192x; 1.1585x over previous
//
#include <hip/hip_runtime.h>
#include <hip/hip_bf16.h>

#define BSZ   4
#define LSEQ  1024
#define NH    12
#define DDIM  768
#define NEN   42
#define NM    96
#define NPAIR (NEN*NEN)   /* 1764 */
#define OFF   1

typedef short bf16x8 __attribute__((ext_vector_type(8)));
typedef float f32x4  __attribute__((ext_vector_type(4)));

__device__ __forceinline__ float bf2f(unsigned short u) {
    union { unsigned u; float f; } c; c.u = ((unsigned)u) << 16; return c.f;
}

typedef const __attribute__((address_space(1))) unsigned int glb_u32;
typedef __attribute__((address_space(3))) unsigned int lds_u32;
__device__ __forceinline__ void glds16(const void* g, void* l) {
    __builtin_amdgcn_global_load_lds((glb_u32*)g, (lds_u32*)l, 16, 0, 0);
}

// ---------------- workspace layout ----------------
// f32: e_emb   then bf16: e_att | ptil | seqT
#define EMB_CNT  (BSZ*NEN*DDIM)
#define EATT_CNT (BSZ*NEN*NH*LSEQ)
#define PTIL_CNT ((size_t)BSZ*NPAIR*LSEQ)

// prep grid: ent_emb (first: longest latency) | ent_att | seq transpose
#define PREP_EMB_BLKS  (BSZ*NEN*3)                 /* 504  */
#define PREP_ATT_BLKS  (BSZ*NEN*NH)                /* 2016 */
#define PREP_T_BLKS    ((LSEQ/32)*(DDIM/32)*BSZ)   /* 3072 */
#define PREP_TOTAL     (PREP_EMB_BLKS + PREP_ATT_BLKS + PREP_T_BLKS)

// pair grid: 6x6 entity tiles (triangular) x 256-l chunks x docs
#define TEN   6
#define NTILE 7                                    /* 42/6 */
#define NTRIT (NTILE*(NTILE+1)/2)                  /* 28 */
#define LCHK  256
#define PAIR_TOTAL (NTRIT*(LSEQ/LCHK)*BSZ)         /* 448 */

// tail grid: fmap blocks first, then gather blocks
#define BM 128
#define BN 64
#define BK 64
#define MT 14           /* ceil(1764/128) */
#define NT (DDIM/BN)    /* 12 */
#define FMAP_BLKS (MT*NT*BSZ)                      /* 672 */
#define GATH_BLKS (BSZ*NPAIR/4)                    /* 1764 */
#define TAIL_TOTAL (FMAP_BLKS + GATH_BLKS)

// ================= kernel 1: fused prep ======================================
__global__ __launch_bounds__(256) void prep_kernel(
        const float* __restrict__ seq,
        const float* __restrict__ att,
        const int* __restrict__ mpos,
        const int* __restrict__ ment,
        float* __restrict__ e_emb,
        __hip_bfloat16* __restrict__ e_att,
        __hip_bfloat16* __restrict__ seqT) {
    __shared__ __align__(16) char smraw[4352];
    const int bid = blockIdx.x;
    const int t = threadIdx.x;

    if (bid < PREP_EMB_BLKS) {
        // ---------- ent_emb: segment logsumexp, one 256-d chunk per block ----
        int chunk = bid % 3;
        int e = (bid / 3) % NEN;
        int b = bid / (3 * NEN);
        int* sp   = (int*)smraw;
        int* se   = sp + NM;
        int* list = se + NM;
        int* pcnt = list + NM;
        if (t < NM) { sp[t] = mpos[b*NM + t] + OFF; se[t] = ment[b*NM + t]; }
        __syncthreads();
        if (t == 0) {                       // deterministic compaction
            int c = 0;
            for (int m = 0; m < NM; ++m) if (se[m] == e) list[c++] = sp[m];
            pcnt[0] = c;
        }
        __syncthreads();
        int cnt = pcnt[0];
        int d = chunk * 256 + t;
        const float* sq = seq + (size_t)b * LSEQ * DDIM + d;
        float mx = -1e30f;
        for (int m = 0; m < cnt; ++m) mx = fmaxf(mx, sq[(size_t)list[m] * DDIM]);
        float out = 0.f;
        if (cnt) {
            float s = 0.f;
            for (int m = 0; m < cnt; ++m) s += expf(sq[(size_t)list[m] * DDIM] - mx);
            out = logf(fmaxf(s, 1e-30f)) + mx;
        }
        e_emb[((size_t)b*NEN + e)*DDIM + d] = out;
    } else if (bid < PREP_EMB_BLKS + PREP_ATT_BLKS) {
        // ---------- ent_att: segment-mean of attention rows -> bf16 ----------
        int id = bid - PREP_EMB_BLKS;
        int h = id % NH;
        int e = (id / NH) % NEN;
        int b = id / (NH * NEN);
        int* sp = (int*)smraw;
        int* se = sp + NM;
        if (t < NM) { sp[t] = mpos[b*NM + t] + OFF; se[t] = ment[b*NM + t]; }
        __syncthreads();
        const float* ab = att + ((size_t)(b*NH + h)) * LSEQ * LSEQ;
        float4 acc = {0.f, 0.f, 0.f, 0.f};
        int cnt = 0;
        for (int m = 0; m < NM; ++m) {
            if (se[m] == e) {
                ++cnt;
                float4 v = ((const float4*)(ab + (size_t)sp[m]*LSEQ))[t];
                acc.x += v.x; acc.y += v.y; acc.z += v.z; acc.w += v.w;
            }
        }
        float inv = cnt ? 1.f / (float)cnt : 0.f;
        union { ushort4 u4; __hip_bfloat16 hh[4]; } pk;
        pk.hh[0] = __float2bfloat16(acc.x * inv);
        pk.hh[1] = __float2bfloat16(acc.y * inv);
        pk.hh[2] = __float2bfloat16(acc.z * inv);
        pk.hh[3] = __float2bfloat16(acc.w * inv);
        ((ushort4*)(e_att + ((size_t)(b*NEN + e)*NH + h)*LSEQ))[t] = pk.u4;
    } else {
        // ---------- seq2bf16T: seq f32 [L][D] -> seqT bf16 [D][L] ------------
        int id = bid - PREP_EMB_BLKS - PREP_ATT_BLKS;
        int l0 = (id % (LSEQ/32)) * 32;
        int d0 = ((id / (LSEQ/32)) % (DDIM/32)) * 32;
        int b  = id / ((LSEQ/32) * (DDIM/32));
        float (*tile)[33] = (float(*)[33])smraw;
        int l = t >> 3, dq = (t & 7) * 4;
        float4 v = *(const float4*)(seq + ((size_t)b*LSEQ + l0 + l)*DDIM + d0 + dq);
        tile[l][dq+0] = v.x; tile[l][dq+1] = v.y;
        tile[l][dq+2] = v.z; tile[l][dq+3] = v.w;
        __syncthreads();
        int d = t >> 3, lq = (t & 7) * 4;
        union { ushort4 u4; __hip_bfloat16 h[4]; } pk;
        pk.h[0] = __float2bfloat16(tile[lq+0][d]);
        pk.h[1] = __float2bfloat16(tile[lq+1][d]);
        pk.h[2] = __float2bfloat16(tile[lq+2][d]);
        pk.h[3] = __float2bfloat16(tile[lq+3][d]);
        *(ushort4*)(seqT + ((size_t)b*DDIM + d0 + d)*LSEQ + l0 + lq) = pk.u4;
    }
}

// ================= kernel 2: pair tiles (6x6 entities, no reductions) ========
__global__ __launch_bounds__(256) void pair_tile_kernel(
        const __hip_bfloat16* __restrict__ e_att,
        __hip_bfloat16* __restrict__ ptil) {
    const int bid = blockIdx.x;
    const int t = threadIdx.x;
    int tri = bid % NTRIT;
    int lc  = (bid / NTRIT) % (LSEQ/LCHK);
    int b   = bid / (NTRIT * (LSEQ/LCHK));
    int ta = 0, rem = tri;
    while (rem >= NTILE - ta) { rem -= NTILE - ta; ++ta; }
    int tb = ta + rem;
    int l = lc * LCHK + t;

    const __hip_bfloat16* ebase = e_att + (size_t)b*NEN*NH*LSEQ + l;
    float s[TEN][TEN];
    #pragma unroll
    for (int i = 0; i < TEN; ++i)
        #pragma unroll
        for (int j = 0; j < TEN; ++j) s[i][j] = 0.f;

    #pragma unroll 4
    for (int h = 0; h < NH; ++h) {
        float xa[TEN], xb[TEN];
        #pragma unroll
        for (int e = 0; e < TEN; ++e)
            xa[e] = bf2f(*(const unsigned short*)(ebase + ((size_t)(ta*TEN+e)*NH + h)*LSEQ));
        #pragma unroll
        for (int e = 0; e < TEN; ++e)
            xb[e] = bf2f(*(const unsigned short*)(ebase + ((size_t)(tb*TEN+e)*NH + h)*LSEQ));
        #pragma unroll
        for (int i = 0; i < TEN; ++i)
            #pragma unroll
            for (int j = 0; j < TEN; ++j)
                s[i][j] += xa[i] * xb[j];
    }

    __hip_bfloat16* pbase = ptil + (size_t)b*NPAIR*LSEQ + l;
    #pragma unroll
    for (int i = 0; i < TEN; ++i) {
        #pragma unroll
        for (int j = 0; j < TEN; ++j) {
            union { unsigned short u; __hip_bfloat16 h; } pk;
            pk.h = __float2bfloat16(s[i][j]);
            int pa = ta*TEN + i, pb = tb*TEN + j;
            *(unsigned short*)(pbase + (size_t)(pa*NEN + pb)*LSEQ) = pk.u;
            if (ta != tb)
                *(unsigned short*)(pbase + (size_t)(pb*NEN + pa)*LSEQ) = pk.u;
        }
    }
}

// ================= kernel 3: tail = fmap GEMM (dbuf glds + rowsum) | gather ==
__global__ __launch_bounds__(256) void tail_kernel(
        const __hip_bfloat16* __restrict__ ptil,
        const __hip_bfloat16* __restrict__ seqT,
        const float* __restrict__ e_emb,
        const int* __restrict__ hts,
        float* __restrict__ out_h,
        float* __restrict__ out_t,
        float* __restrict__ fmap) {
    __shared__ __hip_bfloat16 As[2][BM*BK];     // 2 x 16 KB, XOR-swizzled linear
    __shared__ __hip_bfloat16 Bs[2][BN*BK];     // 2 x  8 KB
    const int bid = blockIdx.x;
    const int t = threadIdx.x;

    if (bid >= FMAP_BLKS) {
        // ---------- gather hss / tss: 4 pairs per block ----------------------
        int id4  = bid - FMAP_BLKS;
        int grp  = t >> 6;
        int lane = t & 63;
        int id   = id4 * 4 + grp;                // b*NPAIR + p
        int b    = id / NPAIR;
        int hi = hts[id*2 + 0];
        int ti = hts[id*2 + 1];
        const float4* eh = (const float4*)(e_emb + ((size_t)(b*NEN + hi))*DDIM);
        const float4* et = (const float4*)(e_emb + ((size_t)(b*NEN + ti))*DDIM);
        float4* oh = (float4*)(out_h + (size_t)id*DDIM);
        float4* ot = (float4*)(out_t + (size_t)id*DDIM);
        #pragma unroll
        for (int i = 0; i < 3; ++i) {            // 192 float4 per row
            oh[lane + 64*i] = eh[lane + 64*i];
            ot[lane + 64*i] = et[lane + 64*i];
        }
        return;
    }

    // ---------- fmap GEMM ----------
    const int lane = t & 63;
    const int wid  = t >> 6;
    const int wr   = wid >> 1;      // 0..1 : 64-row half
    const int wc   = wid & 1;       // 0..1 : 32-col half
    const int bx = bid % MT, by = (bid / MT) % NT, b = bid / (MT*NT);
    const int r0 = bx * BM, c0 = by * BN;

    const char* Ab  = (const char*)(ptil + (size_t)b * NPAIR * LSEQ);
    const char* Btb = (const char*)(seqT + (size_t)b * DDIM * LSEQ);
    char* AsB = (char*)As;
    char* BsB = (char*)Bs;

    const f32x4 zero = {0.f, 0.f, 0.f, 0.f};
    f32x4 acc[4][2];
    #pragma unroll
    for (int m = 0; m < 4; ++m)
        #pragma unroll
        for (int n = 0; n < 2; ++n) acc[m][n] = zero;

    const int fr = lane & 15, kg = lane >> 4;
    const int rs_r = t >> 1, rs_h = t & 1;       // rowsum ownership
    float rsum = 0.f;

#define STAGE(buf, k0)                                                        \
    {                                                                         \
        _Pragma("unroll")                                                     \
        for (int i = 0; i < 4; ++i) {                                         \
            int L = wid*4096 + i*1024 + lane*16;                              \
            int r = L >> 7, beta = L & 127;                                   \
            glds16(Ab + (size_t)(r0 + r)*(LSEQ*2) + (k0)*2                    \
                      + (beta ^ ((r & 7) << 4)), AsB + (buf)*16384 + L);      \
        }                                                                     \
        _Pragma("unroll")                                                     \
        for (int i = 0; i < 2; ++i) {                                         \
            int L = wid*2048 + i*1024 + lane*16;                              \
            int c = L >> 7, beta = L & 127;                                   \
            glds16(Btb + (size_t)(c0 + c)*(LSEQ*2) + (k0)*2                   \
                      + (beta ^ ((c & 7) << 4)), BsB + (buf)*8192 + L);       \
        }                                                                     \
    }

    STAGE(0, 0);
    __syncthreads();

    int cur = 0;
    for (int ki = 0; ki < LSEQ/BK; ++ki) {
        if (ki + 1 < LSEQ/BK) STAGE(cur ^ 1, (ki + 1) * BK);

        const __hip_bfloat16* Ac = (const __hip_bfloat16*)(AsB + cur*16384);
        const __hip_bfloat16* Bc = (const __hip_bfloat16*)(BsB + cur*8192);

        // rowsum of this A-tile (XOR within a row is a bijection -> sum ok)
        #pragma unroll
        for (int jj = 0; jj < 4; ++jj) {
            int e0 = (rs_h*32 + jj*8) ^ ((rs_r & 7) << 3);
            bf16x8 v = *(const bf16x8*)(Ac + rs_r*64 + e0);
            #pragma unroll
            for (int j = 0; j < 8; ++j) rsum += bf2f((unsigned short)v[j]);
        }

        #pragma unroll
        for (int ks = 0; ks < 2; ++ks) {
            bf16x8 af[4], bfv[2];
            #pragma unroll
            for (int m = 0; m < 4; ++m) {
                int R = wr*64 + m*16 + fr;
                int e0 = (ks*32 + kg*8) ^ ((R & 7) << 3);
                af[m] = *(const bf16x8*)(Ac + R*64 + e0);
            }
            #pragma unroll
            for (int n = 0; n < 2; ++n) {
                int C = wc*32 + n*16 + fr;
                int e0 = (ks*32 + kg*8) ^ ((C & 7) << 3);
                bfv[n] = *(const bf16x8*)(Bc + C*64 + e0);
            }
            #pragma unroll
            for (int m = 0; m < 4; ++m)
                #pragma unroll
                for (int n = 0; n < 2; ++n)
                    acc[m][n] = __builtin_amdgcn_mfma_f32_16x16x32_bf16(
                                    af[m], bfv[n], acc[m][n], 0, 0, 0);
        }
        __syncthreads();   // drains glds (vmcnt) + all reads of buf cur done
        cur ^= 1;
    }

    // combine row-sum halves, publish via LDS (buffers now free)
    float rtot = rsum + __shfl_down(rsum, 1);
    float* ssum = (float*)AsB;
    if ((t & 1) == 0) ssum[rs_r] = rtot;
    __syncthreads();

    #pragma unroll
    for (int m = 0; m < 4; ++m) {
        int lr0 = wr*64 + m*16 + kg*4;
        #pragma unroll
        for (int i = 0; i < 4; ++i) {
            int lr = lr0 + i;
            int row = r0 + lr;
            if (row < NPAIR) {
                float sc = 1.f / (ssum[lr] + (float)NH * 1e-5f);
                #pragma unroll
                for (int n = 0; n < 2; ++n) {
                    int col = c0 + wc*32 + n*16 + fr;
                    fmap[((size_t)b*NPAIR + row)*DDIM + col] = acc[m][n][i] * sc;
                }
            }
        }
    }
#undef STAGE
}

// ---------------- launcher ---------------------------------------------------
extern "C" void kernel_launch(void* const* d_in, const int* in_sizes, int n_in,
                              void* d_out, int out_size, void* d_ws, size_t ws_size,
                              hipStream_t stream) {
    const float* seq  = (const float*)d_in[0];
    const float* att  = (const float*)d_in[1];
    const int*   mpos = (const int*)d_in[2];
    const int*   ment = (const int*)d_in[3];
    const int*   hts  = (const int*)d_in[4];

    float* ws_f  = (float*)d_ws;
    float* e_emb = ws_f;
    __hip_bfloat16* e_att = (__hip_bfloat16*)(ws_f + EMB_CNT);
    __hip_bfloat16* ptil  = e_att + EATT_CNT;
    __hip_bfloat16* seqT  = ptil + PTIL_CNT;

    float* out_h = (float*)d_out;
    float* out_t = out_h + (size_t)BSZ*NPAIR*DDIM;
    float* fmap  = out_t + (size_t)BSZ*NPAIR*DDIM;

    hipLaunchKernelGGL(prep_kernel, dim3(PREP_TOTAL), dim3(256), 0, stream,
                       seq, att, mpos, ment, e_emb, e_att, seqT);
    hipLaunchKernelGGL(pair_tile_kernel, dim3(PAIR_TOTAL), dim3(256), 0, stream,
                       e_att, ptil);
    hipLaunchKernelGGL(tail_kernel, dim3(TAIL_TOTAL), dim3(256), 0, stream,
                       ptil, seqT, e_emb, hts, out_h, out_t, fmap);
}

// Round 9
// 56.166 us; speedup vs baseline: 2.5729x; 1.0635x over previous
//
#include <hip/hip_runtime.h>
#include <hip/hip_bf16.h>

#define BSZ   4
#define LSEQ  1024
#define NH    12
#define DDIM  768
#define NEN   42
#define NM    96
#define NPAIR (NEN*NEN)   /* 1764 */
#define OFF   1

typedef short bf16x8 __attribute__((ext_vector_type(8)));
typedef float f32x4  __attribute__((ext_vector_type(4)));

__device__ __forceinline__ float bf2f(unsigned short u) {
    union { unsigned u; float f; } c; c.u = ((unsigned)u) << 16; return c.f;
}

typedef const __attribute__((address_space(1))) unsigned int glb_u32;
typedef __attribute__((address_space(3))) unsigned int lds_u32;
__device__ __forceinline__ void glds16(const void* g, void* l) {
    __builtin_amdgcn_global_load_lds((glb_u32*)g, (lds_u32*)l, 16, 0, 0);
}

// ---------------- workspace layout ----------------
// f32: e_emb | psum   then bf16: e_att | ptil | seqT
#define NLC   4                                     /* l-chunks (LSEQ/LCHK) */
#define EMB_CNT  (BSZ*NEN*DDIM)
#define PSUM_CNT (BSZ*NLC*NPAIR)
#define EATT_CNT (BSZ*NEN*NH*LSEQ)
#define PTIL_CNT ((size_t)BSZ*NPAIR*LSEQ)

// K1: ent_att only
#define ATT_TOTAL (BSZ*NEN*NH)                      /* 2016 */

// K2: pair tiles | seq transpose | ent_emb
#define TEN   6
#define NTILE 7                                     /* 42/6 */
#define NTRIT (NTILE*(NTILE+1)/2)                   /* 28 */
#define LCHK  256
#define PAIR_BLKS (NTRIT*NLC*BSZ)                   /* 448 */
#define T_BLKS    ((LSEQ/32)*(DDIM/32)*BSZ)         /* 3072 */
#define EMB_BLKS  (BSZ*NEN*3)                       /* 504 */
#define MID2_TOTAL (PAIR_BLKS + T_BLKS + EMB_BLKS)

// K3: fmap blocks first (XCD-swizzled), then gather blocks
#define BM 128
#define BN 64
#define BK 64
#define MT 14           /* ceil(1764/128) */
#define NT (DDIM/BN)    /* 12 */
#define FMAP_BLKS (MT*NT*BSZ)                       /* 672, %8==0 */
#define GATH_BLKS (BSZ*NPAIR/4)                     /* 1764 */
#define TAIL_TOTAL (FMAP_BLKS + GATH_BLKS)

// ================= kernel 1: ent_att (segment mean -> bf16) ==================
__global__ __launch_bounds__(256) void att_kernel(
        const float* __restrict__ att,
        const int* __restrict__ mpos,
        const int* __restrict__ ment,
        __hip_bfloat16* __restrict__ e_att) {
    __shared__ int sp[NM];
    __shared__ int se[NM];
    int id = blockIdx.x;
    int h = id % NH;
    int e = (id / NH) % NEN;
    int b = id / (NH * NEN);
    int t = threadIdx.x;
    if (t < NM) { sp[t] = mpos[b*NM + t] + OFF; se[t] = ment[b*NM + t]; }
    __syncthreads();
    const float* ab = att + ((size_t)(b*NH + h)) * LSEQ * LSEQ;
    float4 acc = {0.f, 0.f, 0.f, 0.f};
    int cnt = 0;
    for (int m = 0; m < NM; ++m) {
        if (se[m] == e) {
            ++cnt;
            float4 v = ((const float4*)(ab + (size_t)sp[m]*LSEQ))[t];
            acc.x += v.x; acc.y += v.y; acc.z += v.z; acc.w += v.w;
        }
    }
    float inv = cnt ? 1.f / (float)cnt : 0.f;
    union { ushort4 u4; __hip_bfloat16 hh[4]; } pk;
    pk.hh[0] = __float2bfloat16(acc.x * inv);
    pk.hh[1] = __float2bfloat16(acc.y * inv);
    pk.hh[2] = __float2bfloat16(acc.z * inv);
    pk.hh[3] = __float2bfloat16(acc.w * inv);
    ((ushort4*)(e_att + ((size_t)(b*NEN + e)*NH + h)*LSEQ))[t] = pk.u4;
}

// ================= kernel 2: pair tiles (+psum) | seq2bf16T | ent_emb ========
__global__ __launch_bounds__(256) void mid2_kernel(
        const float* __restrict__ seq,
        const __hip_bfloat16* __restrict__ e_att,
        const int* __restrict__ mpos,
        const int* __restrict__ ment,
        __hip_bfloat16* __restrict__ ptil,
        float* __restrict__ psum,
        __hip_bfloat16* __restrict__ seqT,
        float* __restrict__ e_emb) {
    __shared__ __align__(16) char smraw[4352];
    const int bid = blockIdx.x;
    const int t = threadIdx.x;

    if (bid < PAIR_BLKS) {
        // ---------- pair: 6x6 entity tile x 256-l chunk ----------------------
        int tri = bid % NTRIT;
        int lc  = (bid / NTRIT) % NLC;
        int b   = bid / (NTRIT * NLC);
        int ta = 0, rem = tri;
        while (rem >= NTILE - ta) { rem -= NTILE - ta; ++ta; }
        int tb = ta + rem;
        int l = lc * LCHK + t;

        const __hip_bfloat16* ebase = e_att + (size_t)b*NEN*NH*LSEQ + l;
        float s[TEN][TEN];
        #pragma unroll
        for (int i = 0; i < TEN; ++i)
            #pragma unroll
            for (int j = 0; j < TEN; ++j) s[i][j] = 0.f;

        #pragma unroll 4
        for (int h = 0; h < NH; ++h) {
            float xa[TEN], xb[TEN];
            #pragma unroll
            for (int e = 0; e < TEN; ++e)
                xa[e] = bf2f(*(const unsigned short*)(ebase + ((size_t)(ta*TEN+e)*NH + h)*LSEQ));
            #pragma unroll
            for (int e = 0; e < TEN; ++e)
                xb[e] = bf2f(*(const unsigned short*)(ebase + ((size_t)(tb*TEN+e)*NH + h)*LSEQ));
            #pragma unroll
            for (int i = 0; i < TEN; ++i)
                #pragma unroll
                for (int j = 0; j < TEN; ++j)
                    s[i][j] += xa[i] * xb[j];
        }

        __hip_bfloat16* pbase = ptil + (size_t)b*NPAIR*LSEQ + l;
        #pragma unroll
        for (int i = 0; i < TEN; ++i) {
            #pragma unroll
            for (int j = 0; j < TEN; ++j) {
                union { unsigned short u; __hip_bfloat16 h; } pk;
                pk.h = __float2bfloat16(s[i][j]);
                int pa = ta*TEN + i, pb = tb*TEN + j;
                *(unsigned short*)(pbase + (size_t)(pa*NEN + pb)*LSEQ) = pk.u;
                if (ta != tb)
                    *(unsigned short*)(pbase + (size_t)(pb*NEN + pa)*LSEQ) = pk.u;
            }
        }

        // ---- deterministic partial row sums: wave shfl reduce + LDS combine
        int lane = t & 63, w = t >> 6;
        float (*redp)[TEN*TEN] = (float(*)[TEN*TEN])smraw;  // [4][36]
        float keep = 0.f;
        #pragma unroll
        for (int i = 0; i < TEN; ++i) {
            #pragma unroll
            for (int j = 0; j < TEN; ++j) {
                float v = s[i][j];
                v += __shfl_xor(v,  1, 64);
                v += __shfl_xor(v,  2, 64);
                v += __shfl_xor(v,  4, 64);
                v += __shfl_xor(v,  8, 64);
                v += __shfl_xor(v, 16, 64);
                v += __shfl_xor(v, 32, 64);
                if (lane == i*TEN + j) keep = v;
            }
        }
        if (lane < TEN*TEN) redp[w][lane] = keep;
        __syncthreads();
        if (t < TEN*TEN) {
            float v = redp[0][t] + redp[1][t] + redp[2][t] + redp[3][t];
            int i = t / TEN, j = t % TEN;
            int pa = ta*TEN + i, pb = tb*TEN + j;
            float* ps = psum + ((size_t)(b*NLC + lc))*NPAIR;
            ps[pa*NEN + pb] = v;
            if (ta != tb) ps[pb*NEN + pa] = v;
        }
    } else if (bid < PAIR_BLKS + T_BLKS) {
        // ---------- seq2bf16T: seq f32 [L][D] -> seqT bf16 [D][L] ------------
        int id = bid - PAIR_BLKS;
        int l0 = (id % (LSEQ/32)) * 32;
        int d0 = ((id / (LSEQ/32)) % (DDIM/32)) * 32;
        int b  = id / ((LSEQ/32) * (DDIM/32));
        float (*tile)[33] = (float(*)[33])smraw;
        int l = t >> 3, dq = (t & 7) * 4;
        float4 v = *(const float4*)(seq + ((size_t)b*LSEQ + l0 + l)*DDIM + d0 + dq);
        tile[l][dq+0] = v.x; tile[l][dq+1] = v.y;
        tile[l][dq+2] = v.z; tile[l][dq+3] = v.w;
        __syncthreads();
        int d = t >> 3, lq = (t & 7) * 4;
        union { ushort4 u4; __hip_bfloat16 h[4]; } pk;
        pk.h[0] = __float2bfloat16(tile[lq+0][d]);
        pk.h[1] = __float2bfloat16(tile[lq+1][d]);
        pk.h[2] = __float2bfloat16(tile[lq+2][d]);
        pk.h[3] = __float2bfloat16(tile[lq+3][d]);
        *(ushort4*)(seqT + ((size_t)b*DDIM + d0 + d)*LSEQ + l0 + lq) = pk.u4;
    } else {
        // ---------- ent_emb: segment logsumexp, one 256-d chunk per block ----
        int id = bid - PAIR_BLKS - T_BLKS;
        int chunk = id % 3;
        int e = (id / 3) % NEN;
        int b = id / (3 * NEN);
        int* sp   = (int*)smraw;
        int* se   = sp + NM;
        int* list = se + NM;
        int* pcnt = list + NM;
        if (t < NM) { sp[t] = mpos[b*NM + t] + OFF; se[t] = ment[b*NM + t]; }
        __syncthreads();
        if (t == 0) {
            int c = 0;
            for (int m = 0; m < NM; ++m) if (se[m] == e) list[c++] = sp[m];
            pcnt[0] = c;
        }
        __syncthreads();
        int cnt = pcnt[0];
        int d = chunk * 256 + t;
        const float* sq = seq + (size_t)b * LSEQ * DDIM + d;
        float mx = -1e30f;
        for (int m = 0; m < cnt; ++m) mx = fmaxf(mx, sq[(size_t)list[m] * DDIM]);
        float out = 0.f;
        if (cnt) {
            float s = 0.f;
            for (int m = 0; m < cnt; ++m) s += expf(sq[(size_t)list[m] * DDIM] - mx);
            out = logf(fmaxf(s, 1e-30f)) + mx;
        }
        e_emb[((size_t)b*NEN + e)*DDIM + d] = out;
    }
}

// ================= kernel 3: tail = fmap GEMM (XCD-swz, dbuf) | gather =======
__global__ __launch_bounds__(256) void tail_kernel(
        const __hip_bfloat16* __restrict__ ptil,
        const __hip_bfloat16* __restrict__ seqT,
        const float* __restrict__ psum,
        const float* __restrict__ e_emb,
        const int* __restrict__ hts,
        float* __restrict__ out_h,
        float* __restrict__ out_t,
        float* __restrict__ fmap) {
    __shared__ __hip_bfloat16 As[2][BM*BK];     // 2 x 16 KB, XOR-swizzled linear
    __shared__ __hip_bfloat16 Bs[2][BN*BK];     // 2 x  8 KB
    const int bid = blockIdx.x;
    const int t = threadIdx.x;

    if (bid >= FMAP_BLKS) {
        // ---------- gather hss / tss: 4 pairs per block ----------------------
        int id4  = bid - FMAP_BLKS;
        int grp  = t >> 6;
        int lane = t & 63;
        int id   = id4 * 4 + grp;                // b*NPAIR + p
        int b    = id / NPAIR;
        int hi = hts[id*2 + 0];
        int ti = hts[id*2 + 1];
        const float4* eh = (const float4*)(e_emb + ((size_t)(b*NEN + hi))*DDIM);
        const float4* et = (const float4*)(e_emb + ((size_t)(b*NEN + ti))*DDIM);
        float4* oh = (float4*)(out_h + (size_t)id*DDIM);
        float4* ot = (float4*)(out_t + (size_t)id*DDIM);
        #pragma unroll
        for (int i = 0; i < 3; ++i) {            // 192 float4 per row
            oh[lane + 64*i] = eh[lane + 64*i];
            ot[lane + 64*i] = et[lane + 64*i];
        }
        return;
    }

    // ---------- fmap GEMM (XCD-chunked tile mapping; 672 % 8 == 0) ----------
    int tile = (bid & 7) * (FMAP_BLKS/8) + (bid >> 3);
    const int lane = t & 63;
    const int wid  = t >> 6;
    const int wr   = wid >> 1;      // 0..1 : 64-row half
    const int wc   = wid & 1;       // 0..1 : 32-col half
    const int bx = tile % MT, by = (tile / MT) % NT, b = tile / (MT*NT);
    const int r0 = bx * BM, c0 = by * BN;

    const char* Ab  = (const char*)(ptil + (size_t)b * NPAIR * LSEQ);
    const char* Btb = (const char*)(seqT + (size_t)b * DDIM * LSEQ);
    char* AsB = (char*)As;
    char* BsB = (char*)Bs;

    const f32x4 zero = {0.f, 0.f, 0.f, 0.f};
    f32x4 acc[4][2];
    #pragma unroll
    for (int m = 0; m < 4; ++m)
        #pragma unroll
        for (int n = 0; n < 2; ++n) acc[m][n] = zero;

    const int fr = lane & 15, kg = lane >> 4;

#define STAGE(buf, k0)                                                        \
    {                                                                         \
        _Pragma("unroll")                                                     \
        for (int i = 0; i < 4; ++i) {                                         \
            int L = wid*4096 + i*1024 + lane*16;                              \
            int r = L >> 7, beta = L & 127;                                   \
            glds16(Ab + (size_t)(r0 + r)*(LSEQ*2) + (k0)*2                    \
                      + (beta ^ ((r & 7) << 4)), AsB + (buf)*16384 + L);      \
        }                                                                     \
        _Pragma("unroll")                                                     \
        for (int i = 0; i < 2; ++i) {                                         \
            int L = wid*2048 + i*1024 + lane*16;                              \
            int c = L >> 7, beta = L & 127;                                   \
            glds16(Btb + (size_t)(c0 + c)*(LSEQ*2) + (k0)*2                   \
                      + (beta ^ ((c & 7) << 4)), BsB + (buf)*8192 + L);       \
        }                                                                     \
    }

    STAGE(0, 0);
    __syncthreads();

    int cur = 0;
    for (int ki = 0; ki < LSEQ/BK; ++ki) {
        if (ki + 1 < LSEQ/BK) STAGE(cur ^ 1, (ki + 1) * BK);

        const __hip_bfloat16* Ac = (const __hip_bfloat16*)(AsB + cur*16384);
        const __hip_bfloat16* Bc = (const __hip_bfloat16*)(BsB + cur*8192);

        #pragma unroll
        for (int ks = 0; ks < 2; ++ks) {
            bf16x8 af[4], bfv[2];
            #pragma unroll
            for (int m = 0; m < 4; ++m) {
                int R = wr*64 + m*16 + fr;
                int e0 = (ks*32 + kg*8) ^ ((R & 7) << 3);
                af[m] = *(const bf16x8*)(Ac + R*64 + e0);
            }
            #pragma unroll
            for (int n = 0; n < 2; ++n) {
                int C = wc*32 + n*16 + fr;
                int e0 = (ks*32 + kg*8) ^ ((C & 7) << 3);
                bfv[n] = *(const bf16x8*)(Bc + C*64 + e0);
            }
            #pragma unroll
            for (int m = 0; m < 4; ++m)
                #pragma unroll
                for (int n = 0; n < 2; ++n)
                    acc[m][n] = __builtin_amdgcn_mfma_f32_16x16x32_bf16(
                                    af[m], bfv[n], acc[m][n], 0, 0, 0);
        }
        __syncthreads();   // drains glds (vmcnt); buf cur reads complete
        cur ^= 1;
    }

    // ---- epilogue: invS from psum partials, scale, store ----
    const float* psb = psum + (size_t)b * NLC * NPAIR;
    #pragma unroll
    for (int m = 0; m < 4; ++m) {
        int lr0 = wr*64 + m*16 + kg*4;
        #pragma unroll
        for (int i = 0; i < 4; ++i) {
            int row = r0 + lr0 + i;
            if (row < NPAIR) {
                float S = psb[row] + psb[NPAIR + row]
                        + psb[2*NPAIR + row] + psb[3*NPAIR + row];
                float sc = 1.f / (S + (float)NH * 1e-5f);
                #pragma unroll
                for (int n = 0; n < 2; ++n) {
                    int col = c0 + wc*32 + n*16 + fr;
                    fmap[((size_t)b*NPAIR + row)*DDIM + col] = acc[m][n][i] * sc;
                }
            }
        }
    }
#undef STAGE
}

// ---------------- launcher ---------------------------------------------------
extern "C" void kernel_launch(void* const* d_in, const int* in_sizes, int n_in,
                              void* d_out, int out_size, void* d_ws, size_t ws_size,
                              hipStream_t stream) {
    const float* seq  = (const float*)d_in[0];
    const float* att  = (const float*)d_in[1];
    const int*   mpos = (const int*)d_in[2];
    const int*   ment = (const int*)d_in[3];
    const int*   hts  = (const int*)d_in[4];

    float* ws_f  = (float*)d_ws;
    float* e_emb = ws_f;
    float* psum  = ws_f + EMB_CNT;
    __hip_bfloat16* e_att = (__hip_bfloat16*)(ws_f + EMB_CNT + PSUM_CNT);
    __hip_bfloat16* ptil  = e_att + EATT_CNT;
    __hip_bfloat16* seqT  = ptil + PTIL_CNT;

    float* out_h = (float*)d_out;
    float* out_t = out_h + (size_t)BSZ*NPAIR*DDIM;
    float* fmap  = out_t + (size_t)BSZ*NPAIR*DDIM;

    hipLaunchKernelGGL(att_kernel, dim3(ATT_TOTAL), dim3(256), 0, stream,
                       att, mpos, ment, e_att);
    hipLaunchKernelGGL(mid2_kernel, dim3(MID2_TOTAL), dim3(256), 0, stream,
                       seq, e_att, mpos, ment, ptil, psum, seqT, e_emb);
    hipLaunchKernelGGL(tail_kernel, dim3(TAIL_TOTAL), dim3(256), 0, stream,
                       ptil, seqT, psum, e_emb, hts, out_h, out_t, fmap);
}